// Round 4
// baseline (108.976 us; speedup 1.0000x reference)
//
#include <hip/hip_runtime.h>
#include <cstdint>
#include <cstddef>

// ---- problem constants ----
#define SEQLEN 2048
#define NBATCH 2
#define NIND   256
#define NPOS   256
#define NCIN   512
#define NH     8
#define NDE    64
#define NDV    64
#define NREC   64

typedef __attribute__((ext_vector_type(8))) short s16x8;
typedef __attribute__((ext_vector_type(4))) float f32x4;

__device__ __forceinline__ unsigned short f2bf(float f) {
  union { float f; unsigned u; } v; v.f = f;
  unsigned r = v.u + 0x7fffu + ((v.u >> 16) & 1u);
  return (unsigned short)(r >> 16);
}

// ---------------- prep: concat+pos transpose, all weight cvts, vsum zero ----------------
// blocks [0,512): concat/pos -> xpt[b][l][512] bf16
// blocks [512,1280): Wq/Wk/Wv cvt; [1280,1312): Wc; [1312,1328): Wres;
// [1328,1344): W1; [1344,1360): W2; block 1360: zero vsum.
__global__ __launch_bounds__(256) void prep_k(const float* __restrict__ x,
                                              const float* __restrict__ Wq,
                                              const float* __restrict__ Wk,
                                              const float* __restrict__ Wv,
                                              const float* __restrict__ Wc,
                                              const float* __restrict__ Wres,
                                              const float* __restrict__ W1,
                                              const float* __restrict__ W2,
                                              unsigned short* __restrict__ xpt,
                                              unsigned short* __restrict__ wqb,
                                              unsigned short* __restrict__ wkb,
                                              unsigned short* __restrict__ wvb,
                                              unsigned short* __restrict__ wcb,
                                              unsigned short* __restrict__ wresb,
                                              unsigned short* __restrict__ w1b,
                                              unsigned short* __restrict__ w2b,
                                              float* __restrict__ vsum) {
  __shared__ float tile[64][65];
  int blk = blockIdx.x;
  int t = threadIdx.x;
  if (blk < 512) {
    int b = blk >> 8, c0 = ((blk >> 5) & 7) * 64, l0 = (blk & 31) * 64;
    if (c0 < NIND) {
      const float* src = x + ((size_t)b * NIND + c0) * SEQLEN;
      int ll = t & 63, cq = t >> 6;
#pragma unroll
      for (int i = 0; i < 16; ++i) {
        int cl = cq * 16 + i;
        tile[cl][ll] = src[(size_t)cl * SEQLEN + l0 + ll];
      }
      __syncthreads();
      int cl2 = t & 63, lq = t >> 6;
      unsigned short* dst = xpt + ((size_t)b * SEQLEN + l0) * NCIN + c0;
#pragma unroll
      for (int i = 0; i < 16; ++i) {
        int l = lq * 16 + i;
        dst[(size_t)l * NCIN + cl2] = f2bf(tile[cl2][l]);
      }
    } else {
      int c = c0 + (t & 63);
      int j = c - NIND;
      int i = (j < NPOS / 2) ? j : j - NPOS / 2;
      const double base = (double)1.2f;
      double p = 1.0;
      for (int tt = 0; tt <= i; ++tt) p *= base;
      float w = 0.8f + (float)p;
      float swl = (float)SEQLEN / w;
      const float two_pi = (float)(2.0 * 3.14159265358979323846);
      int wv = t >> 6;
      unsigned short* dst = xpt + (size_t)b * SEQLEN * NCIN;
#pragma unroll
      for (int it = 0; it < 16; ++it) {
        int l = l0 + 16 * wv + it;
        float arg = (two_pi * (float)l) / swl;
        float val = (j < NPOS / 2) ? sinf(arg) : cosf(arg);
        dst[(size_t)l * NCIN + c] = f2bf(val);
      }
    }
  } else if (blk == 1360) {
    ((float4*)vsum)[t] = make_float4(0.f, 0.f, 0.f, 0.f);
  } else {
    const float* in;
    unsigned short* out;
    int idx4;
    if (blk < 1280) {
      int i = (blk - 512) * 256 + t;
      int which = i >> 16;
      idx4 = i & 65535;
      in = (which == 0) ? Wq : ((which == 1) ? Wk : Wv);
      out = (which == 0) ? wqb : ((which == 1) ? wkb : wvb);
    } else if (blk < 1312) { in = Wc;   out = wcb;   idx4 = (blk - 1280) * 256 + t; }
    else if (blk < 1328)   { in = Wres; out = wresb; idx4 = (blk - 1312) * 256 + t; }
    else if (blk < 1344)   { in = W1;   out = w1b;   idx4 = (blk - 1328) * 256 + t; }
    else                   { in = W2;   out = w2b;   idx4 = (blk - 1344) * 256 + t; }
    float4 v = ((const float4*)in)[idx4];
    ((ushort4*)out)[idx4] = make_ushort4(f2bf(v.x), f2bf(v.y), f2bf(v.z), f2bf(v.w));
  }
}

// ---------------- fused QKV MFMA GEMM, BK=64, + V-rowsum atomics ----------------
// Q,K stored transposed [b][h][l][64]; V stored d-major [b][h*64+d][l].
__global__ __launch_bounds__(256) void qkv_gemm_k(const unsigned short* __restrict__ Wqb,
                                                  const unsigned short* __restrict__ Wkb,
                                                  const unsigned short* __restrict__ Wvb,
                                                  const unsigned short* __restrict__ xpt,
                                                  unsigned short* __restrict__ qt,
                                                  unsigned short* __restrict__ kt,
                                                  unsigned short* __restrict__ vb,
                                                  float* __restrict__ vsum) {
  __shared__ alignas(16) unsigned short Al[128][72];
  __shared__ alignas(16) unsigned short Bl[128][72];
  int bz = blockIdx.z;
  int ysel = blockIdx.y >> 2;
  const unsigned short* W = (ysel == 0) ? Wqb : ((ysel == 1) ? Wkb : Wvb);
  unsigned short* C = (ysel == 0) ? qt : ((ysel == 1) ? kt : vb);
  int m0 = (blockIdx.y & 3) * 128;
  int n0 = blockIdx.x * 128;
  const unsigned short* Bg = xpt + (size_t)bz * SEQLEN * NCIN;
  C += (size_t)bz * 512 * SEQLEN;

  int t = threadIdx.x;
  int w = t >> 6, lane = t & 63, lr = lane & 15, hi = lane >> 4;
  int wm = w >> 1, wn = w & 1;
  int srow = t >> 1, sbase = (t & 1) * 32;

  f32x4 acc[4][4];
#pragma unroll
  for (int i = 0; i < 4; ++i)
#pragma unroll
    for (int j = 0; j < 4; ++j) acc[i][j] = (f32x4){0.f, 0.f, 0.f, 0.f};

  for (int k0 = 0; k0 < 512; k0 += 64) {
    int4 ag[4], bg[4];
#pragma unroll
    for (int j = 0; j < 4; ++j) {
      ag[j] = *(const int4*)(W  + (size_t)(m0 + srow) * 512 + k0 + sbase + 8 * j);
      bg[j] = *(const int4*)(Bg + (size_t)(n0 + srow) * 512 + k0 + sbase + 8 * j);
    }
    __syncthreads();
#pragma unroll
    for (int j = 0; j < 4; ++j) {
      *(int4*)&Al[srow][sbase + 8 * j] = ag[j];
      *(int4*)&Bl[srow][sbase + 8 * j] = bg[j];
    }
    __syncthreads();
#pragma unroll
    for (int ks = 0; ks < 2; ++ks) {
      s16x8 af[4], bfv[4];
#pragma unroll
      for (int mt = 0; mt < 4; ++mt) af[mt]  = *(const s16x8*)&Al[64 * wm + 16 * mt + lr][32 * ks + 8 * hi];
#pragma unroll
      for (int nt = 0; nt < 4; ++nt) bfv[nt] = *(const s16x8*)&Bl[64 * wn + 16 * nt + lr][32 * ks + 8 * hi];
#pragma unroll
      for (int mt = 0; mt < 4; ++mt)
#pragma unroll
        for (int nt = 0; nt < 4; ++nt)
          acc[mt][nt] = __builtin_amdgcn_mfma_f32_16x16x32_bf16(af[mt], bfv[nt], acc[mt][nt], 0, 0, 0);
    }
  }

  if (ysel < 2) {
    // transposed store: [h][l][d]
#pragma unroll
    for (int mt = 0; mt < 4; ++mt) {
      int mm = m0 + 64 * wm + 16 * mt;
      int h = mm >> 6;
      int d0 = (mm & 63) + 4 * hi;
#pragma unroll
      for (int nt = 0; nt < 4; ++nt) {
        int n = n0 + 64 * wn + 16 * nt + lr;
        ushort4 o = make_ushort4(f2bf(acc[mt][nt][0]), f2bf(acc[mt][nt][1]),
                                 f2bf(acc[mt][nt][2]), f2bf(acc[mt][nt][3]));
        *(ushort4*)&C[((size_t)h * SEQLEN + n) * 64 + d0] = o;
      }
    }
  } else {
    // d-major store + per-row partial sums into vsum
#pragma unroll
    for (int mt = 0; mt < 4; ++mt)
#pragma unroll
      for (int nt = 0; nt < 4; ++nt) {
        int n = n0 + 64 * wn + 16 * nt + lr;
#pragma unroll
        for (int reg = 0; reg < 4; ++reg) {
          int m = m0 + 64 * wm + 16 * mt + 4 * hi + reg;
          C[(size_t)m * SEQLEN + n] = f2bf(acc[mt][nt][reg]);
        }
      }
#pragma unroll
    for (int mt = 0; mt < 4; ++mt)
#pragma unroll
      for (int reg = 0; reg < 4; ++reg) {
        float p = acc[mt][0][reg] + acc[mt][1][reg] + acc[mt][2][reg] + acc[mt][3][reg];
        p += __shfl_xor(p, 1, 64);
        p += __shfl_xor(p, 2, 64);
        p += __shfl_xor(p, 4, 64);
        p += __shfl_xor(p, 8, 64);
        if (lr == 0)
          atomicAdd(&vsum[bz * 512 + m0 + 64 * wm + 16 * mt + 4 * hi + reg], p);
      }
  }
}

// ---------------- banded attention, MFMA, direct-global fragments ----------------
__global__ __launch_bounds__(256) void attn_k(const unsigned short* __restrict__ qt,
                                              const unsigned short* __restrict__ kt,
                                              const unsigned short* __restrict__ vb,
                                              const float* __restrict__ vsum,
                                              unsigned short* __restrict__ attnt) {
  __shared__ alignas(16) unsigned short Ps[64 * 200];
  __shared__ float rowcoef[64];

  int bz = blockIdx.z, hh = blockIdx.y;
  int l0 = blockIdx.x * 64;
  int bh = bz * NH + hh;
  const unsigned short* Qb = qt + (size_t)bh * SEQLEN * 64;
  const unsigned short* Kb = kt + (size_t)bh * SEQLEN * 64;
  const unsigned short* Vp = vb + (size_t)(bz * 512 + hh * 64) * SEQLEN;
  int vsbase = bz * 512 + hh * 64;

  int t = threadIdx.x;
  int w = t >> 6, lane = t & 63, lr = lane & 15, hi = lane >> 4;

  union U { int4 i4; s16x8 v; };

  U a0, a1;
  a0.v = *(const s16x8*)(Qb + ((size_t)(l0 + 16 * w + lr)) * 64 + 8 * hi);
  a1.v = *(const s16x8*)(Qb + ((size_t)(l0 + 16 * w + lr)) * 64 + 32 + 8 * hi);

  f32x4 sc[12];
#pragma unroll
  for (int ct = 0; ct < 12; ++ct) {
    int m = l0 - 64 + 16 * ct + lr;
    U b0, b1;
    b0.i4 = make_int4(0, 0, 0, 0);
    b1.i4 = make_int4(0, 0, 0, 0);
    if (m >= 0 && m < SEQLEN) {
      b0.v = *(const s16x8*)(Kb + (size_t)m * 64 + 8 * hi);
      b1.v = *(const s16x8*)(Kb + (size_t)m * 64 + 32 + 8 * hi);
    }
    f32x4 acc = {0.f, 0.f, 0.f, 0.f};
    acc = __builtin_amdgcn_mfma_f32_16x16x32_bf16(a0.v, b0.v, acc, 0, 0, 0);
    acc = __builtin_amdgcn_mfma_f32_16x16x32_bf16(a1.v, b1.v, acc, 0, 0, 0);
    sc[ct] = acc;
  }

  float rcv[4];
#pragma unroll
  for (int i = 0; i < 4; ++i) {
    int r = 16 * w + 4 * hi + i;
    int l = l0 + r;
    float mx = 0.0f;
    float sv[12];
#pragma unroll
    for (int ct = 0; ct < 12; ++ct) {
      int c = 16 * ct + lr;
      int m = l0 - 64 + c;
      bool ib = (c >= r) && (c <= r + 128) && (m >= 0) && (m < SEQLEN);
      float s = sc[ct][i] * 0.125f;
      sv[ct] = ib ? s : -1e30f;
      mx = ib ? fmaxf(mx, s) : mx;
    }
    mx = fmaxf(mx, __shfl_xor(mx, 1, 64));
    mx = fmaxf(mx, __shfl_xor(mx, 2, 64));
    mx = fmaxf(mx, __shfl_xor(mx, 4, 64));
    mx = fmaxf(mx, __shfl_xor(mx, 8, 64));
    float e0 = expf(-mx);
    float zs = 0.f;
#pragma unroll
    for (int ct = 0; ct < 12; ++ct) {
      float e = (sv[ct] > -1e29f) ? expf(sv[ct] - mx) : 0.0f;
      sv[ct] = e;
      zs += e;
    }
    zs += __shfl_xor(zs, 1, 64);
    zs += __shfl_xor(zs, 2, 64);
    zs += __shfl_xor(zs, 4, 64);
    zs += __shfl_xor(zs, 8, 64);
    int lo = l - NREC; if (lo < 0) lo = 0;
    int hi2 = l + NREC; if (hi2 > SEQLEN - 1) hi2 = SEQLEN - 1;
    float inv = 1.0f / (zs + (float)(SEQLEN - (hi2 - lo + 1)) * e0);
    rcv[i] = e0 * inv;
#pragma unroll
    for (int ct = 0; ct < 12; ++ct)
      sc[ct][i] = (sv[ct] > 0.0f) ? (sv[ct] - e0) * inv : 0.0f;
  }

#pragma unroll
  for (int i = 0; i < 4; ++i) {
    int r = 16 * w + 4 * hi + i;
#pragma unroll
    for (int ct = 0; ct < 12; ++ct)
      Ps[r * 200 + 16 * ct + lr] = f2bf(sc[ct][i]);
  }
  if (lr == 0) {
#pragma unroll
    for (int i = 0; i < 4; ++i) rowcoef[16 * w + 4 * hi + i] = rcv[i];
  }
  __syncthreads();

  U av[6];
#pragma unroll
  for (int ks = 0; ks < 6; ++ks) {
    int m8 = l0 - 64 + 32 * ks + 8 * hi;
    av[ks].i4 = make_int4(0, 0, 0, 0);
    if (m8 >= 0 && m8 < SEQLEN)
      av[ks].v = *(const s16x8*)(Vp + (size_t)(16 * w + lr) * SEQLEN + m8);
  }
  float vsv[4];
#pragma unroll
  for (int reg = 0; reg < 4; ++reg) vsv[reg] = vsum[vsbase + 16 * w + 4 * hi + reg];

  unsigned short* Ob = attnt + ((size_t)bz * SEQLEN) * 512 + hh * 64;
#pragma unroll
  for (int nt = 0; nt < 4; ++nt) {
    f32x4 acc = {0.f, 0.f, 0.f, 0.f};
#pragma unroll
    for (int ks = 0; ks < 6; ++ks) {
      s16x8 b = *(const s16x8*)&Ps[(16 * nt + lr) * 200 + 32 * ks + 8 * hi];
      acc = __builtin_amdgcn_mfma_f32_16x16x32_bf16(av[ks].v, b, acc, 0, 0, 0);
    }
    int l = l0 + 16 * nt + lr;
    float rcf = rowcoef[16 * nt + lr];
    ushort4 o = make_ushort4(f2bf(acc[0] + rcf * vsv[0]), f2bf(acc[1] + rcf * vsv[1]),
                             f2bf(acc[2] + rcf * vsv[2]), f2bf(acc[3] + rcf * vsv[3]));
    *(ushort4*)&Ob[(size_t)l * 512 + 16 * w + 4 * hi] = o;
  }
}

// ---------------- fused tail: LN1(Wc@attn + Wres@x) -> gelu(W1@..) -> LN2(W2@.. + res) ----------------
// One block per (b, 64-l tile). A-fragments direct from global bf16 weights.
__global__ __launch_bounds__(256) void tail_k(const unsigned short* __restrict__ wcb,
                                              const unsigned short* __restrict__ wresb,
                                              const unsigned short* __restrict__ w1b,
                                              const unsigned short* __restrict__ w2b,
                                              const unsigned short* __restrict__ attnt,
                                              const unsigned short* __restrict__ xpt,
                                              const float* __restrict__ g1v,
                                              const float* __restrict__ b1v,
                                              const float* __restrict__ g2v,
                                              const float* __restrict__ b2v,
                                              float* __restrict__ outp) {
  __shared__ float pred32[64][68];
  __shared__ alignas(16) unsigned short predbf[64][72];
  __shared__ alignas(16) unsigned short hls[64][264];
  __shared__ float gs1[64], bs1[64], gs2[64], bs2[64];

  int b = blockIdx.y;
  int l0 = blockIdx.x * 64;
  int t = threadIdx.x, w = t >> 6, lane = t & 63, lr = lane & 15, hi = lane >> 4;
  if (t < 64) { gs1[t] = g1v[t]; bs1[t] = b1v[t]; gs2[t] = g2v[t]; bs2[t] = b2v[t]; }
  __syncthreads();

  int lloc = 16 * w + lr;
  // ---- phase 1: pred = LN1(Wc @ attnt + Wres @ x) ----
  const unsigned short* brow = attnt + ((size_t)b * SEQLEN + l0 + lloc) * 512;
  const unsigned short* xrow = xpt + ((size_t)b * SEQLEN + l0 + lloc) * 512;
  f32x4 acc[4];
#pragma unroll
  for (int i = 0; i < 4; ++i) acc[i] = (f32x4){0.f, 0.f, 0.f, 0.f};
#pragma unroll
  for (int ks = 0; ks < 16; ++ks) {
    s16x8 bf = *(const s16x8*)(brow + 32 * ks + 8 * hi);
#pragma unroll
    for (int mt = 0; mt < 4; ++mt) {
      s16x8 af = *(const s16x8*)(wcb + (size_t)(16 * mt + lr) * 512 + 32 * ks + 8 * hi);
      acc[mt] = __builtin_amdgcn_mfma_f32_16x16x32_bf16(af, bf, acc[mt], 0, 0, 0);
    }
  }
#pragma unroll
  for (int ks = 0; ks < 8; ++ks) {
    s16x8 bf = *(const s16x8*)(xrow + 32 * ks + 8 * hi);
#pragma unroll
    for (int mt = 0; mt < 4; ++mt) {
      s16x8 af = *(const s16x8*)(wresb + (size_t)(16 * mt + lr) * 256 + 32 * ks + 8 * hi);
      acc[mt] = __builtin_amdgcn_mfma_f32_16x16x32_bf16(af, bf, acc[mt], 0, 0, 0);
    }
  }
  {
    float sum = 0.f, sq = 0.f;
#pragma unroll
    for (int mt = 0; mt < 4; ++mt)
#pragma unroll
      for (int reg = 0; reg < 4; ++reg) { float v = acc[mt][reg]; sum += v; sq += v * v; }
    sum += __shfl_xor(sum, 16, 64); sq += __shfl_xor(sq, 16, 64);
    sum += __shfl_xor(sum, 32, 64); sq += __shfl_xor(sq, 32, 64);
    float mu = sum * (1.0f / 64.0f);
    float var = sq * (1.0f / 64.0f) - mu * mu;
    float rstd = rsqrtf(var + 1e-5f);
#pragma unroll
    for (int mt = 0; mt < 4; ++mt) {
      float o[4];
#pragma unroll
      for (int reg = 0; reg < 4; ++reg) {
        int m = 16 * mt + 4 * hi + reg;
        o[reg] = (acc[mt][reg] - mu) * rstd * gs1[m] + bs1[m];
      }
      *(float4*)&pred32[lloc][16 * mt + 4 * hi] = make_float4(o[0], o[1], o[2], o[3]);
      *(ushort4*)&predbf[lloc][16 * mt + 4 * hi] =
          make_ushort4(f2bf(o[0]), f2bf(o[1]), f2bf(o[2]), f2bf(o[3]));
    }
  }
  __syncthreads();

  // ---- phase 2: h = gelu(W1 @ pred) -> hls ----
  {
    s16x8 bf0[4], bf1[4];
#pragma unroll
    for (int nt = 0; nt < 4; ++nt) {
      bf0[nt] = *(const s16x8*)&predbf[16 * nt + lr][8 * hi];
      bf1[nt] = *(const s16x8*)&predbf[16 * nt + lr][32 + 8 * hi];
    }
#pragma unroll
    for (int mt = 0; mt < 4; ++mt) {
      int m = 64 * w + 16 * mt + lr;
      s16x8 a0 = *(const s16x8*)(w1b + (size_t)m * 64 + 8 * hi);
      s16x8 a1 = *(const s16x8*)(w1b + (size_t)m * 64 + 32 + 8 * hi);
#pragma unroll
      for (int nt = 0; nt < 4; ++nt) {
        f32x4 a2 = {0.f, 0.f, 0.f, 0.f};
        a2 = __builtin_amdgcn_mfma_f32_16x16x32_bf16(a0, bf0[nt], a2, 0, 0, 0);
        a2 = __builtin_amdgcn_mfma_f32_16x16x32_bf16(a1, bf1[nt], a2, 0, 0, 0);
        float v0 = a2[0], v1 = a2[1], v2 = a2[2], v3 = a2[3];
        v0 = 0.5f * v0 * (1.0f + erff(v0 * 0.70710678118654752440f));
        v1 = 0.5f * v1 * (1.0f + erff(v1 * 0.70710678118654752440f));
        v2 = 0.5f * v2 * (1.0f + erff(v2 * 0.70710678118654752440f));
        v3 = 0.5f * v3 * (1.0f + erff(v3 * 0.70710678118654752440f));
        *(ushort4*)&hls[16 * nt + lr][64 * w + 16 * mt + 4 * hi] =
            make_ushort4(f2bf(v0), f2bf(v1), f2bf(v2), f2bf(v3));
      }
    }
  }
  __syncthreads();

  // ---- phase 3: out = LN2(W2 @ h + pred) (transpose-store) ----
  f32x4 acc3[4];
#pragma unroll
  for (int i = 0; i < 4; ++i) acc3[i] = (f32x4){0.f, 0.f, 0.f, 0.f};
#pragma unroll
  for (int ks = 0; ks < 8; ++ks) {
    s16x8 bf = *(const s16x8*)&hls[lloc][32 * ks + 8 * hi];
#pragma unroll
    for (int mt = 0; mt < 4; ++mt) {
      s16x8 af = *(const s16x8*)(w2b + (size_t)(16 * mt + lr) * 256 + 32 * ks + 8 * hi);
      acc3[mt] = __builtin_amdgcn_mfma_f32_16x16x32_bf16(af, bf, acc3[mt], 0, 0, 0);
    }
  }
#pragma unroll
  for (int mt = 0; mt < 4; ++mt) {
    float4 r = *(const float4*)&pred32[lloc][16 * mt + 4 * hi];
    acc3[mt][0] += r.x; acc3[mt][1] += r.y; acc3[mt][2] += r.z; acc3[mt][3] += r.w;
  }
  float sum = 0.f, sq = 0.f;
#pragma unroll
  for (int mt = 0; mt < 4; ++mt)
#pragma unroll
    for (int reg = 0; reg < 4; ++reg) { float v = acc3[mt][reg]; sum += v; sq += v * v; }
  sum += __shfl_xor(sum, 16, 64); sq += __shfl_xor(sq, 16, 64);
  sum += __shfl_xor(sum, 32, 64); sq += __shfl_xor(sq, 32, 64);
  float mu = sum * (1.0f / 64.0f);
  float var = sq * (1.0f / 64.0f) - mu * mu;
  float rstd = rsqrtf(var + 1e-5f);
  float* ob = outp + (size_t)b * 64 * SEQLEN;
  int l = l0 + lloc;
#pragma unroll
  for (int mt = 0; mt < 4; ++mt)
#pragma unroll
    for (int reg = 0; reg < 4; ++reg) {
      int m = 16 * mt + 4 * hi + reg;
      ob[(size_t)m * SEQLEN + l] = (acc3[mt][reg] - mu) * rstd * gs2[m] + bs2[m];
    }
}

extern "C" void kernel_launch(void* const* d_in, const int* in_sizes, int n_in,
                              void* d_out, int out_size, void* d_ws, size_t ws_size,
                              hipStream_t stream) {
  const float* x    = (const float*)d_in[0];
  const float* Wq   = (const float*)d_in[1];
  const float* Wk   = (const float*)d_in[2];
  const float* Wv   = (const float*)d_in[3];
  const float* Wres = (const float*)d_in[4];
  const float* Wc   = (const float*)d_in[5];
  const float* ln1g = (const float*)d_in[6];
  const float* ln1b = (const float*)d_in[7];
  const float* W1   = (const float*)d_in[8];
  const float* W2   = (const float*)d_in[9];
  const float* ln2g = (const float*)d_in[10];
  const float* ln2b = (const float*)d_in[11];

  char* base = (char*)d_ws;
  unsigned short* xpt   = (unsigned short*)base; base += (size_t)2097152 * 2;
  unsigned short* wqb   = (unsigned short*)base; base += (size_t)262144 * 2;
  unsigned short* wkb   = (unsigned short*)base; base += (size_t)262144 * 2;
  unsigned short* wvb   = (unsigned short*)base; base += (size_t)262144 * 2;
  unsigned short* wcb   = (unsigned short*)base; base += (size_t)32768 * 2;
  unsigned short* wresb = (unsigned short*)base; base += (size_t)16384 * 2;
  unsigned short* w1b   = (unsigned short*)base; base += (size_t)16384 * 2;
  unsigned short* w2b   = (unsigned short*)base; base += (size_t)16384 * 2;
  unsigned short* qt    = (unsigned short*)base; base += (size_t)2097152 * 2;
  unsigned short* kt    = (unsigned short*)base; base += (size_t)2097152 * 2;
  unsigned short* vbb   = (unsigned short*)base; base += (size_t)2097152 * 2;
  float* vsum           = (float*)base;          base += (size_t)1024 * 4;
  unsigned short* attnt = (unsigned short*)base; base += (size_t)2097152 * 2;
  float* outp = (float*)d_out;

  prep_k<<<1361, 256, 0, stream>>>(x, Wq, Wk, Wv, Wc, Wres, W1, W2,
                                   xpt, wqb, wkb, wvb, wcb, wresb, w1b, w2b, vsum);
  qkv_gemm_k<<<dim3(16, 12, NBATCH), 256, 0, stream>>>(wqb, wkb, wvb, xpt, qt, kt, vbb, vsum);
  attn_k<<<dim3(32, NH, NBATCH), 256, 0, stream>>>(qt, kt, vbb, vsum, attnt);
  tail_k<<<dim3(32, NBATCH), 256, 0, stream>>>(wcb, wresb, w1b, w2b, attnt, xpt,
                                               ln1g, ln1b, ln2g, ln2b, outp);
}

// Round 5
// 101.824 us; speedup vs baseline: 1.0702x; 1.0702x over previous
//
#include <hip/hip_runtime.h>
#include <cstdint>
#include <cstddef>

// ---- problem constants ----
#define SEQLEN 2048
#define NBATCH 2
#define NIND   256
#define NPOS   256
#define NCIN   512
#define NH     8
#define NDE    64
#define NDV    64
#define NREC   64

typedef __attribute__((ext_vector_type(8))) short s16x8;
typedef __attribute__((ext_vector_type(4))) float f32x4;

__device__ __forceinline__ unsigned short f2bf(float f) {
  union { float f; unsigned u; } v; v.f = f;
  unsigned r = v.u + 0x7fffu + ((v.u >> 16) & 1u);
  return (unsigned short)(r >> 16);
}

// ---------------- prep: concat+pos transpose, all weight cvts, vsum zero ----------------
__global__ __launch_bounds__(256) void prep_k(const float* __restrict__ x,
                                              const float* __restrict__ Wq,
                                              const float* __restrict__ Wk,
                                              const float* __restrict__ Wv,
                                              const float* __restrict__ Wc,
                                              const float* __restrict__ Wres,
                                              const float* __restrict__ W1,
                                              const float* __restrict__ W2,
                                              unsigned short* __restrict__ xpt,
                                              unsigned short* __restrict__ wqb,
                                              unsigned short* __restrict__ wkb,
                                              unsigned short* __restrict__ wvb,
                                              unsigned short* __restrict__ wcb,
                                              unsigned short* __restrict__ wresb,
                                              unsigned short* __restrict__ w1b,
                                              unsigned short* __restrict__ w2b,
                                              float* __restrict__ vsum) {
  __shared__ float tile[64][65];
  int blk = blockIdx.x;
  int t = threadIdx.x;
  if (blk < 512) {
    int b = blk >> 8, c0 = ((blk >> 5) & 7) * 64, l0 = (blk & 31) * 64;
    if (c0 < NIND) {
      const float* src = x + ((size_t)b * NIND + c0) * SEQLEN;
      int ll = t & 63, cq = t >> 6;
#pragma unroll
      for (int i = 0; i < 16; ++i) {
        int cl = cq * 16 + i;
        tile[cl][ll] = src[(size_t)cl * SEQLEN + l0 + ll];
      }
      __syncthreads();
      int cl2 = t & 63, lq = t >> 6;
      unsigned short* dst = xpt + ((size_t)b * SEQLEN + l0) * NCIN + c0;
#pragma unroll
      for (int i = 0; i < 16; ++i) {
        int l = lq * 16 + i;
        dst[(size_t)l * NCIN + cl2] = f2bf(tile[cl2][l]);
      }
    } else {
      int c = c0 + (t & 63);
      int j = c - NIND;
      int i = (j < NPOS / 2) ? j : j - NPOS / 2;
      const double base = (double)1.2f;
      double p = 1.0;
      for (int tt = 0; tt <= i; ++tt) p *= base;
      float w = 0.8f + (float)p;
      float swl = (float)SEQLEN / w;
      const float two_pi = (float)(2.0 * 3.14159265358979323846);
      int wv = t >> 6;
      unsigned short* dst = xpt + (size_t)b * SEQLEN * NCIN;
#pragma unroll
      for (int it = 0; it < 16; ++it) {
        int l = l0 + 16 * wv + it;
        float arg = (two_pi * (float)l) / swl;
        float val = (j < NPOS / 2) ? sinf(arg) : cosf(arg);
        dst[(size_t)l * NCIN + c] = f2bf(val);
      }
    }
  } else if (blk == 1360) {
    ((float4*)vsum)[t] = make_float4(0.f, 0.f, 0.f, 0.f);
  } else {
    const float* in;
    unsigned short* out;
    int idx4;
    if (blk < 1280) {
      int i = (blk - 512) * 256 + t;
      int which = i >> 16;
      idx4 = i & 65535;
      in = (which == 0) ? Wq : ((which == 1) ? Wk : Wv);
      out = (which == 0) ? wqb : ((which == 1) ? wkb : wvb);
    } else if (blk < 1312) { in = Wc;   out = wcb;   idx4 = (blk - 1280) * 256 + t; }
    else if (blk < 1328)   { in = Wres; out = wresb; idx4 = (blk - 1312) * 256 + t; }
    else if (blk < 1344)   { in = W1;   out = w1b;   idx4 = (blk - 1328) * 256 + t; }
    else                   { in = W2;   out = w2b;   idx4 = (blk - 1344) * 256 + t; }
    float4 v = ((const float4*)in)[idx4];
    ((ushort4*)out)[idx4] = make_ushort4(f2bf(v.x), f2bf(v.y), f2bf(v.z), f2bf(v.w));
  }
}

// ---------------- fused QKV MFMA GEMM, 64x128 tiles, BK=64, LDS-staged epilogue ----------------
// grid (16 n-tiles, 24 m-tiles [8 per matrix], NBATCH).
// Q,K stored [b][h][l][64]; V stored [b][h*64+d][l]. vsum accumulated via atomics.
__global__ __launch_bounds__(256) void qkv_gemm_k(const unsigned short* __restrict__ Wqb,
                                                  const unsigned short* __restrict__ Wkb,
                                                  const unsigned short* __restrict__ Wvb,
                                                  const unsigned short* __restrict__ xpt,
                                                  unsigned short* __restrict__ qt,
                                                  unsigned short* __restrict__ kt,
                                                  unsigned short* __restrict__ vb,
                                                  float* __restrict__ vsum) {
  __shared__ alignas(16) unsigned short lds[64 * 72 + 128 * 72];
  unsigned short* Al = lds;             // [64][72]
  unsigned short* Bl = lds + 64 * 72;   // [128][72]

  int bz = blockIdx.z;
  int y = blockIdx.y;                   // 0..23
  int ysel = y >> 3;
  int m0 = (y & 7) * 64;
  int n0 = blockIdx.x * 128;
  const unsigned short* W = (ysel == 0) ? Wqb : ((ysel == 1) ? Wkb : Wvb);
  const unsigned short* Bg = xpt + (size_t)bz * SEQLEN * NCIN;

  int t = threadIdx.x;
  int w = t >> 6, lane = t & 63, lr = lane & 15, hi = lane >> 4;
  int wm = w >> 1, wn = w & 1;
  int arow = t >> 2, acol = (t & 3) * 8;   // A stage: +0, +32
  int brow = t >> 1, bcol = (t & 1) * 32;  // B stage: +8j

  f32x4 acc[2][4];
#pragma unroll
  for (int i = 0; i < 2; ++i)
#pragma unroll
    for (int j = 0; j < 4; ++j) acc[i][j] = (f32x4){0.f, 0.f, 0.f, 0.f};

  for (int k0 = 0; k0 < 512; k0 += 64) {
    int4 a0 = *(const int4*)(W + (size_t)(m0 + arow) * 512 + k0 + acol);
    int4 a1 = *(const int4*)(W + (size_t)(m0 + arow) * 512 + k0 + acol + 32);
    int4 bg[4];
#pragma unroll
    for (int j = 0; j < 4; ++j)
      bg[j] = *(const int4*)(Bg + (size_t)(n0 + brow) * 512 + k0 + bcol + 8 * j);
    __syncthreads();
    *(int4*)&Al[arow * 72 + acol] = a0;
    *(int4*)&Al[arow * 72 + acol + 32] = a1;
#pragma unroll
    for (int j = 0; j < 4; ++j)
      *(int4*)&Bl[brow * 72 + bcol + 8 * j] = bg[j];
    __syncthreads();
#pragma unroll
    for (int ks = 0; ks < 2; ++ks) {
      s16x8 af[2], bfv[4];
#pragma unroll
      for (int mt = 0; mt < 2; ++mt)
        af[mt] = *(const s16x8*)&Al[(32 * wm + 16 * mt + lr) * 72 + 32 * ks + 8 * hi];
#pragma unroll
      for (int nt = 0; nt < 4; ++nt)
        bfv[nt] = *(const s16x8*)&Bl[(64 * wn + 16 * nt + lr) * 72 + 32 * ks + 8 * hi];
#pragma unroll
      for (int mt = 0; mt < 2; ++mt)
#pragma unroll
        for (int nt = 0; nt < 4; ++nt)
          acc[mt][nt] = __builtin_amdgcn_mfma_f32_16x16x32_bf16(af[mt], bfv[nt], acc[mt][nt], 0, 0, 0);
    }
  }

  if (ysel == 2) {
    // vsum partial sums (over this block's 128 columns)
#pragma unroll
    for (int mt = 0; mt < 2; ++mt)
#pragma unroll
      for (int reg = 0; reg < 4; ++reg) {
        float p = acc[mt][0][reg] + acc[mt][1][reg] + acc[mt][2][reg] + acc[mt][3][reg];
        p += __shfl_xor(p, 1, 64);
        p += __shfl_xor(p, 2, 64);
        p += __shfl_xor(p, 4, 64);
        p += __shfl_xor(p, 8, 64);
        if (lr == 0)
          atomicAdd(&vsum[bz * 512 + m0 + 32 * wm + 16 * mt + 4 * hi + reg], p);
      }
  }
  __syncthreads();   // Al/Bl dead; reuse for C staging

  if (ysel < 2) {
    // stage Cl[l 128][d 64] pitch 68, then coalesced 128B-row stores
    unsigned short* Cl = lds;
#pragma unroll
    for (int mt = 0; mt < 2; ++mt)
#pragma unroll
      for (int nt = 0; nt < 4; ++nt) {
        int lloc = 64 * wn + 16 * nt + lr;
        int d0 = 32 * wm + 16 * mt + 4 * hi;
        *(ushort4*)&Cl[lloc * 68 + d0] = make_ushort4(f2bf(acc[mt][nt][0]), f2bf(acc[mt][nt][1]),
                                                      f2bf(acc[mt][nt][2]), f2bf(acc[mt][nt][3]));
      }
    __syncthreads();
    int h = m0 >> 6;
    unsigned short* Cb = ((ysel == 0) ? qt : kt) + ((size_t)(bz * NH + h) * SEQLEN + n0) * 64;
    int rr = t >> 1, cc = (t & 1) * 32;
#pragma unroll
    for (int j = 0; j < 4; ++j)
      *(int4*)&Cb[(size_t)rr * 64 + cc + 8 * j] = *(const int4*)&Cl[rr * 68 + cc + 8 * j];
  } else {
    // stage Cl2[d 64][l 128] pitch 132, then coalesced 256B-row stores
    unsigned short* Cl2 = lds;
#pragma unroll
    for (int mt = 0; mt < 2; ++mt)
#pragma unroll
      for (int nt = 0; nt < 4; ++nt) {
        int lloc = 64 * wn + 16 * nt + lr;
#pragma unroll
        for (int reg = 0; reg < 4; ++reg)
          Cl2[(32 * wm + 16 * mt + 4 * hi + reg) * 132 + lloc] = f2bf(acc[mt][nt][reg]);
      }
    __syncthreads();
    int dd = t >> 2, cc = (t & 3) * 32;
    unsigned short* Vb = vb + ((size_t)(bz * 512 + m0 + dd)) * SEQLEN + n0;
#pragma unroll
    for (int j = 0; j < 4; ++j)
      *(int4*)&Vb[cc + 8 * j] = *(const int4*)&Cl2[dd * 132 + cc + 8 * j];
  }
}

// ---------------- banded attention, MFMA, direct-global fragments ----------------
__global__ __launch_bounds__(256) void attn_k(const unsigned short* __restrict__ qt,
                                              const unsigned short* __restrict__ kt,
                                              const unsigned short* __restrict__ vb,
                                              const float* __restrict__ vsum,
                                              unsigned short* __restrict__ attnt) {
  __shared__ alignas(16) unsigned short Ps[64 * 200];
  __shared__ float rowcoef[64];

  int bz = blockIdx.z, hh = blockIdx.y;
  int l0 = blockIdx.x * 64;
  int bh = bz * NH + hh;
  const unsigned short* Qb = qt + (size_t)bh * SEQLEN * 64;
  const unsigned short* Kb = kt + (size_t)bh * SEQLEN * 64;
  const unsigned short* Vp = vb + (size_t)(bz * 512 + hh * 64) * SEQLEN;
  int vsbase = bz * 512 + hh * 64;

  int t = threadIdx.x;
  int w = t >> 6, lane = t & 63, lr = lane & 15, hi = lane >> 4;

  union U { int4 i4; s16x8 v; };

  U a0, a1;
  a0.v = *(const s16x8*)(Qb + ((size_t)(l0 + 16 * w + lr)) * 64 + 8 * hi);
  a1.v = *(const s16x8*)(Qb + ((size_t)(l0 + 16 * w + lr)) * 64 + 32 + 8 * hi);

  f32x4 sc[12];
#pragma unroll
  for (int ct = 0; ct < 12; ++ct) {
    int m = l0 - 64 + 16 * ct + lr;
    U b0, b1;
    b0.i4 = make_int4(0, 0, 0, 0);
    b1.i4 = make_int4(0, 0, 0, 0);
    if (m >= 0 && m < SEQLEN) {
      b0.v = *(const s16x8*)(Kb + (size_t)m * 64 + 8 * hi);
      b1.v = *(const s16x8*)(Kb + (size_t)m * 64 + 32 + 8 * hi);
    }
    f32x4 acc = {0.f, 0.f, 0.f, 0.f};
    acc = __builtin_amdgcn_mfma_f32_16x16x32_bf16(a0.v, b0.v, acc, 0, 0, 0);
    acc = __builtin_amdgcn_mfma_f32_16x16x32_bf16(a1.v, b1.v, acc, 0, 0, 0);
    sc[ct] = acc;
  }

  float rcv[4];
#pragma unroll
  for (int i = 0; i < 4; ++i) {
    int r = 16 * w + 4 * hi + i;
    int l = l0 + r;
    float mx = 0.0f;
    float sv[12];
#pragma unroll
    for (int ct = 0; ct < 12; ++ct) {
      int c = 16 * ct + lr;
      int m = l0 - 64 + c;
      bool ib = (c >= r) && (c <= r + 128) && (m >= 0) && (m < SEQLEN);
      float s = sc[ct][i] * 0.125f;
      sv[ct] = ib ? s : -1e30f;
      mx = ib ? fmaxf(mx, s) : mx;
    }
    mx = fmaxf(mx, __shfl_xor(mx, 1, 64));
    mx = fmaxf(mx, __shfl_xor(mx, 2, 64));
    mx = fmaxf(mx, __shfl_xor(mx, 4, 64));
    mx = fmaxf(mx, __shfl_xor(mx, 8, 64));
    float e0 = expf(-mx);
    float zs = 0.f;
#pragma unroll
    for (int ct = 0; ct < 12; ++ct) {
      float e = (sv[ct] > -1e29f) ? expf(sv[ct] - mx) : 0.0f;
      sv[ct] = e;
      zs += e;
    }
    zs += __shfl_xor(zs, 1, 64);
    zs += __shfl_xor(zs, 2, 64);
    zs += __shfl_xor(zs, 4, 64);
    zs += __shfl_xor(zs, 8, 64);
    int lo = l - NREC; if (lo < 0) lo = 0;
    int hi2 = l + NREC; if (hi2 > SEQLEN - 1) hi2 = SEQLEN - 1;
    float inv = 1.0f / (zs + (float)(SEQLEN - (hi2 - lo + 1)) * e0);
    rcv[i] = e0 * inv;
#pragma unroll
    for (int ct = 0; ct < 12; ++ct)
      sc[ct][i] = (sv[ct] > 0.0f) ? (sv[ct] - e0) * inv : 0.0f;
  }

#pragma unroll
  for (int i = 0; i < 4; ++i) {
    int r = 16 * w + 4 * hi + i;
#pragma unroll
    for (int ct = 0; ct < 12; ++ct)
      Ps[r * 200 + 16 * ct + lr] = f2bf(sc[ct][i]);
  }
  if (lr == 0) {
#pragma unroll
    for (int i = 0; i < 4; ++i) rowcoef[16 * w + 4 * hi + i] = rcv[i];
  }
  __syncthreads();

  U av[6];
#pragma unroll
  for (int ks = 0; ks < 6; ++ks) {
    int m8 = l0 - 64 + 32 * ks + 8 * hi;
    av[ks].i4 = make_int4(0, 0, 0, 0);
    if (m8 >= 0 && m8 < SEQLEN)
      av[ks].v = *(const s16x8*)(Vp + (size_t)(16 * w + lr) * SEQLEN + m8);
  }
  float vsv[4];
#pragma unroll
  for (int reg = 0; reg < 4; ++reg) vsv[reg] = vsum[vsbase + 16 * w + 4 * hi + reg];

  unsigned short* Ob = attnt + ((size_t)bz * SEQLEN) * 512 + hh * 64;
#pragma unroll
  for (int nt = 0; nt < 4; ++nt) {
    f32x4 acc = {0.f, 0.f, 0.f, 0.f};
#pragma unroll
    for (int ks = 0; ks < 6; ++ks) {
      s16x8 b = *(const s16x8*)&Ps[(16 * nt + lr) * 200 + 32 * ks + 8 * hi];
      acc = __builtin_amdgcn_mfma_f32_16x16x32_bf16(av[ks].v, b, acc, 0, 0, 0);
    }
    int l = l0 + 16 * nt + lr;
    float rcf = rowcoef[16 * nt + lr];
    ushort4 o = make_ushort4(f2bf(acc[0] + rcf * vsv[0]), f2bf(acc[1] + rcf * vsv[1]),
                             f2bf(acc[2] + rcf * vsv[2]), f2bf(acc[3] + rcf * vsv[3]));
    *(ushort4*)&Ob[(size_t)l * 512 + 16 * w + 4 * hi] = o;
  }
}

// ---------------- fused tail, wave-independent phases ----------------
// Block (b, 64-l tile); wave w owns cols l0+16w+[0,16). No cross-wave barriers
// after the g/b broadcast: per-wave LDS slices + lgkmcnt fences.
__global__ __launch_bounds__(256) void tail_k(const unsigned short* __restrict__ wcb,
                                              const unsigned short* __restrict__ wresb,
                                              const unsigned short* __restrict__ w1b,
                                              const unsigned short* __restrict__ w2b,
                                              const unsigned short* __restrict__ attnt,
                                              const unsigned short* __restrict__ xpt,
                                              const float* __restrict__ g1v,
                                              const float* __restrict__ b1v,
                                              const float* __restrict__ g2v,
                                              const float* __restrict__ b2v,
                                              float* __restrict__ outp) {
  __shared__ float gs1[64], bs1[64], gs2[64], bs2[64];
  __shared__ alignas(16) unsigned short pw[4][16][72];
  __shared__ alignas(16) unsigned short hw[4][16][264];

  int b = blockIdx.y;
  int l0 = blockIdx.x * 64;
  int t = threadIdx.x, w = t >> 6, lane = t & 63, lr = lane & 15, hi = lane >> 4;
  if (t < 64) { gs1[t] = g1v[t]; bs1[t] = b1v[t]; gs2[t] = g2v[t]; bs2[t] = b2v[t]; }
  __syncthreads();

  int lloc = 16 * w + lr;
  const unsigned short* brow = attnt + ((size_t)b * SEQLEN + l0 + lloc) * 512;
  const unsigned short* xrow = xpt + ((size_t)b * SEQLEN + l0 + lloc) * 512;

  // ---- phase 1: pred = LN1(Wc @ attnt + Wres @ x) ----
  f32x4 acc[4];
#pragma unroll
  for (int i = 0; i < 4; ++i) acc[i] = (f32x4){0.f, 0.f, 0.f, 0.f};
#pragma unroll
  for (int ks = 0; ks < 16; ++ks) {
    s16x8 bf = *(const s16x8*)(brow + 32 * ks + 8 * hi);
#pragma unroll
    for (int mt = 0; mt < 4; ++mt) {
      s16x8 af = *(const s16x8*)(wcb + (size_t)(16 * mt + lr) * 512 + 32 * ks + 8 * hi);
      acc[mt] = __builtin_amdgcn_mfma_f32_16x16x32_bf16(af, bf, acc[mt], 0, 0, 0);
    }
  }
#pragma unroll
  for (int ks = 0; ks < 8; ++ks) {
    s16x8 bf = *(const s16x8*)(xrow + 32 * ks + 8 * hi);
#pragma unroll
    for (int mt = 0; mt < 4; ++mt) {
      s16x8 af = *(const s16x8*)(wresb + (size_t)(16 * mt + lr) * 256 + 32 * ks + 8 * hi);
      acc[mt] = __builtin_amdgcn_mfma_f32_16x16x32_bf16(af, bf, acc[mt], 0, 0, 0);
    }
  }
  float resid[4][4];
  {
    float sum = 0.f, sq = 0.f;
#pragma unroll
    for (int mt = 0; mt < 4; ++mt)
#pragma unroll
      for (int reg = 0; reg < 4; ++reg) { float v = acc[mt][reg]; sum += v; sq += v * v; }
    sum += __shfl_xor(sum, 16, 64); sq += __shfl_xor(sq, 16, 64);
    sum += __shfl_xor(sum, 32, 64); sq += __shfl_xor(sq, 32, 64);
    float mu = sum * (1.0f / 64.0f);
    float var = sq * (1.0f / 64.0f) - mu * mu;
    float rstd = rsqrtf(var + 1e-5f);
#pragma unroll
    for (int mt = 0; mt < 4; ++mt) {
      float o[4];
#pragma unroll
      for (int reg = 0; reg < 4; ++reg) {
        int m = 16 * mt + 4 * hi + reg;
        o[reg] = (acc[mt][reg] - mu) * rstd * gs1[m] + bs1[m];
        resid[mt][reg] = o[reg];
      }
      *(ushort4*)&pw[w][lr][16 * mt + 4 * hi] =
          make_ushort4(f2bf(o[0]), f2bf(o[1]), f2bf(o[2]), f2bf(o[3]));
    }
  }
  asm volatile("s_waitcnt lgkmcnt(0)" ::: "memory");

  // ---- phase 2: h = gelu(W1 @ pred) ----
  {
    s16x8 bf0 = *(const s16x8*)&pw[w][lr][8 * hi];
    s16x8 bf1 = *(const s16x8*)&pw[w][lr][32 + 8 * hi];
#pragma unroll
    for (int mt = 0; mt < 16; ++mt) {
      s16x8 a0 = *(const s16x8*)(w1b + (size_t)(16 * mt + lr) * 64 + 8 * hi);
      s16x8 a1 = *(const s16x8*)(w1b + (size_t)(16 * mt + lr) * 64 + 32 + 8 * hi);
      f32x4 a2 = {0.f, 0.f, 0.f, 0.f};
      a2 = __builtin_amdgcn_mfma_f32_16x16x32_bf16(a0, bf0, a2, 0, 0, 0);
      a2 = __builtin_amdgcn_mfma_f32_16x16x32_bf16(a1, bf1, a2, 0, 0, 0);
      float v0 = a2[0], v1 = a2[1], v2 = a2[2], v3 = a2[3];
      v0 = 0.5f * v0 * (1.0f + erff(v0 * 0.70710678118654752440f));
      v1 = 0.5f * v1 * (1.0f + erff(v1 * 0.70710678118654752440f));
      v2 = 0.5f * v2 * (1.0f + erff(v2 * 0.70710678118654752440f));
      v3 = 0.5f * v3 * (1.0f + erff(v3 * 0.70710678118654752440f));
      *(ushort4*)&hw[w][lr][16 * mt + 4 * hi] = make_ushort4(f2bf(v0), f2bf(v1), f2bf(v2), f2bf(v3));
    }
  }
  asm volatile("s_waitcnt lgkmcnt(0)" ::: "memory");

  // ---- phase 3: out = LN2(W2 @ h + pred) ----
  f32x4 acc3[4];
#pragma unroll
  for (int i = 0; i < 4; ++i) acc3[i] = (f32x4){0.f, 0.f, 0.f, 0.f};
#pragma unroll
  for (int ks = 0; ks < 8; ++ks) {
    s16x8 bf = *(const s16x8*)&hw[w][lr][32 * ks + 8 * hi];
#pragma unroll
    for (int mt = 0; mt < 4; ++mt) {
      s16x8 af = *(const s16x8*)(w2b + (size_t)(16 * mt + lr) * 256 + 32 * ks + 8 * hi);
      acc3[mt] = __builtin_amdgcn_mfma_f32_16x16x32_bf16(af, bf, acc3[mt], 0, 0, 0);
    }
  }
#pragma unroll
  for (int mt = 0; mt < 4; ++mt)
#pragma unroll
    for (int reg = 0; reg < 4; ++reg) acc3[mt][reg] += resid[mt][reg];
  float sum = 0.f, sq = 0.f;
#pragma unroll
  for (int mt = 0; mt < 4; ++mt)
#pragma unroll
    for (int reg = 0; reg < 4; ++reg) { float v = acc3[mt][reg]; sum += v; sq += v * v; }
  sum += __shfl_xor(sum, 16, 64); sq += __shfl_xor(sq, 16, 64);
  sum += __shfl_xor(sum, 32, 64); sq += __shfl_xor(sq, 32, 64);
  float mu = sum * (1.0f / 64.0f);
  float var = sq * (1.0f / 64.0f) - mu * mu;
  float rstd = rsqrtf(var + 1e-5f);
  float* ob = outp + (size_t)b * 64 * SEQLEN;
  int l = l0 + lloc;
#pragma unroll
  for (int mt = 0; mt < 4; ++mt)
#pragma unroll
    for (int reg = 0; reg < 4; ++reg) {
      int m = 16 * mt + 4 * hi + reg;
      ob[(size_t)m * SEQLEN + l] = (acc3[mt][reg] - mu) * rstd * gs2[m] + bs2[m];
    }
}

extern "C" void kernel_launch(void* const* d_in, const int* in_sizes, int n_in,
                              void* d_out, int out_size, void* d_ws, size_t ws_size,
                              hipStream_t stream) {
  const float* x    = (const float*)d_in[0];
  const float* Wq   = (const float*)d_in[1];
  const float* Wk   = (const float*)d_in[2];
  const float* Wv   = (const float*)d_in[3];
  const float* Wres = (const float*)d_in[4];
  const float* Wc   = (const float*)d_in[5];
  const float* ln1g = (const float*)d_in[6];
  const float* ln1b = (const float*)d_in[7];
  const float* W1   = (const float*)d_in[8];
  const float* W2   = (const float*)d_in[9];
  const float* ln2g = (const float*)d_in[10];
  const float* ln2b = (const float*)d_in[11];

  char* base = (char*)d_ws;
  unsigned short* xpt   = (unsigned short*)base; base += (size_t)2097152 * 2;
  unsigned short* wqb   = (unsigned short*)base; base += (size_t)262144 * 2;
  unsigned short* wkb   = (unsigned short*)base; base += (size_t)262144 * 2;
  unsigned short* wvb   = (unsigned short*)base; base += (size_t)262144 * 2;
  unsigned short* wcb   = (unsigned short*)base; base += (size_t)32768 * 2;
  unsigned short* wresb = (unsigned short*)base; base += (size_t)16384 * 2;
  unsigned short* w1b   = (unsigned short*)base; base += (size_t)16384 * 2;
  unsigned short* w2b   = (unsigned short*)base; base += (size_t)16384 * 2;
  unsigned short* qt    = (unsigned short*)base; base += (size_t)2097152 * 2;
  unsigned short* kt    = (unsigned short*)base; base += (size_t)2097152 * 2;
  unsigned short* vbb   = (unsigned short*)base; base += (size_t)2097152 * 2;
  float* vsum           = (float*)base;          base += (size_t)1024 * 4;
  unsigned short* attnt = (unsigned short*)base; base += (size_t)2097152 * 2;
  float* outp = (float*)d_out;

  prep_k<<<1361, 256, 0, stream>>>(x, Wq, Wk, Wv, Wc, Wres, W1, W2,
                                   xpt, wqb, wkb, wvb, wcb, wresb, w1b, w2b, vsum);
  qkv_gemm_k<<<dim3(16, 24, NBATCH), 256, 0, stream>>>(wqb, wkb, wvb, xpt, qt, kt, vbb, vsum);
  attn_k<<<dim3(32, NH, NBATCH), 256, 0, stream>>>(qt, kt, vbb, vsum, attnt);
  tail_k<<<dim3(32, NBATCH), 256, 0, stream>>>(wcb, wresb, w1b, w2b, attnt, xpt,
                                               ln1g, ln1b, ln2g, ln2b, outp);
}

// Round 6
// 80.205 us; speedup vs baseline: 1.3587x; 1.2695x over previous
//
#include <hip/hip_runtime.h>
#include <cstdint>
#include <cstddef>

// ---- problem constants ----
#define SEQLEN 2048
#define NBATCH 2
#define NIND   256
#define NPOS   256
#define NCIN   512
#define NH     8
#define NDE    64
#define NDV    64
#define NREC   64

typedef __attribute__((ext_vector_type(8))) short s16x8;
typedef __attribute__((ext_vector_type(4))) float f32x4;

__device__ __forceinline__ unsigned short f2bf(float f) {
  union { float f; unsigned u; } v; v.f = f;
  unsigned r = v.u + 0x7fffu + ((v.u >> 16) & 1u);
  return (unsigned short)(r >> 16);
}

// async global->LDS, 16B per lane; LDS dest = wave-uniform base + lane*16
__device__ __forceinline__ void gload16(const unsigned short* g, unsigned short* l) {
  __builtin_amdgcn_global_load_lds(
      (const __attribute__((address_space(1))) unsigned int*)g,
      (__attribute__((address_space(3))) unsigned int*)l, 16, 0, 0);
}

// ---------------- prep: concat+pos transpose, all weight cvts, vsum zero ----------------
__global__ __launch_bounds__(256) void prep_k(const float* __restrict__ x,
                                              const float* __restrict__ Wq,
                                              const float* __restrict__ Wk,
                                              const float* __restrict__ Wv,
                                              const float* __restrict__ Wc,
                                              const float* __restrict__ Wres,
                                              const float* __restrict__ W1,
                                              const float* __restrict__ W2,
                                              unsigned short* __restrict__ xpt,
                                              unsigned short* __restrict__ wqb,
                                              unsigned short* __restrict__ wkb,
                                              unsigned short* __restrict__ wvb,
                                              unsigned short* __restrict__ wcb,
                                              unsigned short* __restrict__ wresb,
                                              unsigned short* __restrict__ w1b,
                                              unsigned short* __restrict__ w2b,
                                              float* __restrict__ vsum) {
  __shared__ float tile[64][65];
  int blk = blockIdx.x;
  int t = threadIdx.x;
  if (blk < 512) {
    int b = blk >> 8, c0 = ((blk >> 5) & 7) * 64, l0 = (blk & 31) * 64;
    if (c0 < NIND) {
      const float* src = x + ((size_t)b * NIND + c0) * SEQLEN;
      int ll = t & 63, cq = t >> 6;
#pragma unroll
      for (int i = 0; i < 16; ++i) {
        int cl = cq * 16 + i;
        tile[cl][ll] = src[(size_t)cl * SEQLEN + l0 + ll];
      }
      __syncthreads();
      int cl2 = t & 63, lq = t >> 6;
      unsigned short* dst = xpt + ((size_t)b * SEQLEN + l0) * NCIN + c0;
#pragma unroll
      for (int i = 0; i < 16; ++i) {
        int l = lq * 16 + i;
        dst[(size_t)l * NCIN + cl2] = f2bf(tile[cl2][l]);
      }
    } else {
      int c = c0 + (t & 63);
      int j = c - NIND;
      int i = (j < NPOS / 2) ? j : j - NPOS / 2;
      const double base = (double)1.2f;
      double p = 1.0;
      for (int tt = 0; tt <= i; ++tt) p *= base;
      float w = 0.8f + (float)p;
      float swl = (float)SEQLEN / w;
      const float two_pi = (float)(2.0 * 3.14159265358979323846);
      int wv = t >> 6;
      unsigned short* dst = xpt + (size_t)b * SEQLEN * NCIN;
#pragma unroll
      for (int it = 0; it < 16; ++it) {
        int l = l0 + 16 * wv + it;
        float arg = (two_pi * (float)l) / swl;
        float val = (j < NPOS / 2) ? sinf(arg) : cosf(arg);
        dst[(size_t)l * NCIN + c] = f2bf(val);
      }
    }
  } else if (blk == 1360) {
    ((float4*)vsum)[t] = make_float4(0.f, 0.f, 0.f, 0.f);
  } else {
    const float* in;
    unsigned short* out;
    int idx4;
    if (blk < 1280) {
      int i = (blk - 512) * 256 + t;
      int which = i >> 16;
      idx4 = i & 65535;
      in = (which == 0) ? Wq : ((which == 1) ? Wk : Wv);
      out = (which == 0) ? wqb : ((which == 1) ? wkb : wvb);
    } else if (blk < 1312) { in = Wc;   out = wcb;   idx4 = (blk - 1280) * 256 + t; }
    else if (blk < 1328)   { in = Wres; out = wresb; idx4 = (blk - 1312) * 256 + t; }
    else if (blk < 1344)   { in = W1;   out = w1b;   idx4 = (blk - 1328) * 256 + t; }
    else                   { in = W2;   out = w2b;   idx4 = (blk - 1344) * 256 + t; }
    float4 v = ((const float4*)in)[idx4];
    ((ushort4*)out)[idx4] = make_ushort4(f2bf(v.x), f2bf(v.y), f2bf(v.z), f2bf(v.w));
  }
}

// ---------------- fused QKV MFMA GEMM: 64x128, BK=64, global_load_lds + T2 swizzle ----------------
// LDS linear [row][64] shorts; source pre-swizzled (chunk^row&7), ds_read col ^ ((lr&7)<<3).
// grid (16 n-tiles, 24 m-tiles, NBATCH). Q,K -> [b][h][l][64]; V -> [b][h*64+d][l].
__global__ __launch_bounds__(256) void qkv_gemm_k(const unsigned short* __restrict__ Wqb,
                                                  const unsigned short* __restrict__ Wkb,
                                                  const unsigned short* __restrict__ Wvb,
                                                  const unsigned short* __restrict__ xpt,
                                                  unsigned short* __restrict__ qt,
                                                  unsigned short* __restrict__ kt,
                                                  unsigned short* __restrict__ vb,
                                                  float* __restrict__ vsum) {
  __shared__ alignas(16) unsigned short lds[12288];   // A 64x64 | B 128x64
  unsigned short* Al = lds;
  unsigned short* Bl = lds + 4096;

  int bz = blockIdx.z;
  int y = blockIdx.y;
  int ysel = y >> 3;
  int m0 = (y & 7) * 64;
  int n0 = blockIdx.x * 128;
  const unsigned short* W = (ysel == 0) ? Wqb : ((ysel == 1) ? Wkb : Wvb);
  const unsigned short* Bg = xpt + (size_t)bz * SEQLEN * NCIN;

  int t = threadIdx.x;
  int w = t >> 6, lane = t & 63, lr = lane & 15, hi = lane >> 4;
  int wm = w >> 1, wn = w & 1;

  // staging: lane -> (row-in-8-group, chunk); source chunk pre-swizzled by row
  int sr = lane >> 3;
  int scs = ((lane & 7) ^ sr) * 8;   // shorts
  const unsigned short* gA0 = W  + (size_t)(m0 + 16 * w + sr) * 512 + scs;
  const unsigned short* gB0 = Bg + (size_t)(n0 + 32 * w + sr) * 512 + scs;
  unsigned short* lA0 = &Al[(16 * w) * 64];
  unsigned short* lB0 = &Bl[(32 * w) * 64];

  int swz = (lr & 7) << 3;           // read-side XOR (shorts)

  f32x4 acc[2][4];
#pragma unroll
  for (int i = 0; i < 2; ++i)
#pragma unroll
    for (int j = 0; j < 4; ++j) acc[i][j] = (f32x4){0.f, 0.f, 0.f, 0.f};

  for (int k0 = 0; k0 < 512; k0 += 64) {
    __syncthreads();                 // prior MFMA reads drained before overwrite
    gload16(gA0 + k0,            lA0);
    gload16(gA0 + k0 + 8 * 512,  lA0 + 8 * 64);
    gload16(gB0 + k0,            lB0);
    gload16(gB0 + k0 + 8 * 512,  lB0 + 8 * 64);
    gload16(gB0 + k0 + 16 * 512, lB0 + 16 * 64);
    gload16(gB0 + k0 + 24 * 512, lB0 + 24 * 64);
    __syncthreads();                 // vmcnt(0) drain inside barrier
#pragma unroll
    for (int ks = 0; ks < 2; ++ks) {
      s16x8 af[2], bfv[4];
#pragma unroll
      for (int mt = 0; mt < 2; ++mt)
        af[mt] = *(const s16x8*)&Al[(32 * wm + 16 * mt + lr) * 64 + ((32 * ks + 8 * hi) ^ swz)];
#pragma unroll
      for (int nt = 0; nt < 4; ++nt)
        bfv[nt] = *(const s16x8*)&Bl[(64 * wn + 16 * nt + lr) * 64 + ((32 * ks + 8 * hi) ^ swz)];
#pragma unroll
      for (int mt = 0; mt < 2; ++mt)
#pragma unroll
        for (int nt = 0; nt < 4; ++nt)
          acc[mt][nt] = __builtin_amdgcn_mfma_f32_16x16x32_bf16(af[mt], bfv[nt], acc[mt][nt], 0, 0, 0);
    }
  }

  if (ysel == 2) {
    // vsum partial sums (over this block's 128 columns)
#pragma unroll
    for (int mt = 0; mt < 2; ++mt)
#pragma unroll
      for (int reg = 0; reg < 4; ++reg) {
        float p = acc[mt][0][reg] + acc[mt][1][reg] + acc[mt][2][reg] + acc[mt][3][reg];
        p += __shfl_xor(p, 1, 64);
        p += __shfl_xor(p, 2, 64);
        p += __shfl_xor(p, 4, 64);
        p += __shfl_xor(p, 8, 64);
        if (lr == 0)
          atomicAdd(&vsum[bz * 512 + m0 + 32 * wm + 16 * mt + 4 * hi + reg], p);
      }
  }
  __syncthreads();   // lds dead; reuse for C staging

  if (ysel < 2) {
    // stage Cl[l 128][d 64] pitch 68, then coalesced 128B-row stores
    unsigned short* Cl = lds;
#pragma unroll
    for (int mt = 0; mt < 2; ++mt)
#pragma unroll
      for (int nt = 0; nt < 4; ++nt) {
        int lloc = 64 * wn + 16 * nt + lr;
        int d0 = 32 * wm + 16 * mt + 4 * hi;
        *(ushort4*)&Cl[lloc * 68 + d0] = make_ushort4(f2bf(acc[mt][nt][0]), f2bf(acc[mt][nt][1]),
                                                      f2bf(acc[mt][nt][2]), f2bf(acc[mt][nt][3]));
      }
    __syncthreads();
    int h = m0 >> 6;
    unsigned short* Cb = ((ysel == 0) ? qt : kt) + ((size_t)(bz * NH + h) * SEQLEN + n0) * 64;
    int rr = t >> 1, cc = (t & 1) * 32;
#pragma unroll
    for (int j = 0; j < 4; ++j)
      *(int4*)&Cb[(size_t)rr * 64 + cc + 8 * j] = *(const int4*)&Cl[rr * 68 + cc + 8 * j];
  } else {
    // stage Cl2[d 64][l 128] pitch 132, then coalesced 256B-row stores
    unsigned short* Cl2 = lds;
#pragma unroll
    for (int mt = 0; mt < 2; ++mt)
#pragma unroll
      for (int nt = 0; nt < 4; ++nt) {
        int lloc = 64 * wn + 16 * nt + lr;
#pragma unroll
        for (int reg = 0; reg < 4; ++reg)
          Cl2[(32 * wm + 16 * mt + 4 * hi + reg) * 132 + lloc] = f2bf(acc[mt][nt][reg]);
      }
    __syncthreads();
    int dd = t >> 2, cc = (t & 3) * 32;
    unsigned short* Vb = vb + ((size_t)(bz * 512 + m0 + dd)) * SEQLEN + n0;
#pragma unroll
    for (int j = 0; j < 4; ++j)
      *(int4*)&Vb[cc + 8 * j] = *(const int4*)&Cl2[dd * 132 + cc + 8 * j];
  }
}

// ---------------- banded attention, MFMA, direct-global fragments ----------------
__global__ __launch_bounds__(256) void attn_k(const unsigned short* __restrict__ qt,
                                              const unsigned short* __restrict__ kt,
                                              const unsigned short* __restrict__ vb,
                                              const float* __restrict__ vsum,
                                              unsigned short* __restrict__ attnt) {
  __shared__ alignas(16) unsigned short Ps[64 * 200];
  __shared__ float rowcoef[64];

  int bz = blockIdx.z, hh = blockIdx.y;
  int l0 = blockIdx.x * 64;
  int bh = bz * NH + hh;
  const unsigned short* Qb = qt + (size_t)bh * SEQLEN * 64;
  const unsigned short* Kb = kt + (size_t)bh * SEQLEN * 64;
  const unsigned short* Vp = vb + (size_t)(bz * 512 + hh * 64) * SEQLEN;
  int vsbase = bz * 512 + hh * 64;

  int t = threadIdx.x;
  int w = t >> 6, lane = t & 63, lr = lane & 15, hi = lane >> 4;

  union U { int4 i4; s16x8 v; };

  U a0, a1;
  a0.v = *(const s16x8*)(Qb + ((size_t)(l0 + 16 * w + lr)) * 64 + 8 * hi);
  a1.v = *(const s16x8*)(Qb + ((size_t)(l0 + 16 * w + lr)) * 64 + 32 + 8 * hi);

  f32x4 sc[12];
#pragma unroll
  for (int ct = 0; ct < 12; ++ct) {
    int m = l0 - 64 + 16 * ct + lr;
    U b0, b1;
    b0.i4 = make_int4(0, 0, 0, 0);
    b1.i4 = make_int4(0, 0, 0, 0);
    if (m >= 0 && m < SEQLEN) {
      b0.v = *(const s16x8*)(Kb + (size_t)m * 64 + 8 * hi);
      b1.v = *(const s16x8*)(Kb + (size_t)m * 64 + 32 + 8 * hi);
    }
    f32x4 acc = {0.f, 0.f, 0.f, 0.f};
    acc = __builtin_amdgcn_mfma_f32_16x16x32_bf16(a0.v, b0.v, acc, 0, 0, 0);
    acc = __builtin_amdgcn_mfma_f32_16x16x32_bf16(a1.v, b1.v, acc, 0, 0, 0);
    sc[ct] = acc;
  }

  float rcv[4];
#pragma unroll
  for (int i = 0; i < 4; ++i) {
    int r = 16 * w + 4 * hi + i;
    int l = l0 + r;
    float mx = 0.0f;
    float sv[12];
#pragma unroll
    for (int ct = 0; ct < 12; ++ct) {
      int c = 16 * ct + lr;
      int m = l0 - 64 + c;
      bool ib = (c >= r) && (c <= r + 128) && (m >= 0) && (m < SEQLEN);
      float s = sc[ct][i] * 0.125f;
      sv[ct] = ib ? s : -1e30f;
      mx = ib ? fmaxf(mx, s) : mx;
    }
    mx = fmaxf(mx, __shfl_xor(mx, 1, 64));
    mx = fmaxf(mx, __shfl_xor(mx, 2, 64));
    mx = fmaxf(mx, __shfl_xor(mx, 4, 64));
    mx = fmaxf(mx, __shfl_xor(mx, 8, 64));
    float e0 = expf(-mx);
    float zs = 0.f;
#pragma unroll
    for (int ct = 0; ct < 12; ++ct) {
      float e = (sv[ct] > -1e29f) ? expf(sv[ct] - mx) : 0.0f;
      sv[ct] = e;
      zs += e;
    }
    zs += __shfl_xor(zs, 1, 64);
    zs += __shfl_xor(zs, 2, 64);
    zs += __shfl_xor(zs, 4, 64);
    zs += __shfl_xor(zs, 8, 64);
    int lo = l - NREC; if (lo < 0) lo = 0;
    int hi2 = l + NREC; if (hi2 > SEQLEN - 1) hi2 = SEQLEN - 1;
    float inv = 1.0f / (zs + (float)(SEQLEN - (hi2 - lo + 1)) * e0);
    rcv[i] = e0 * inv;
#pragma unroll
    for (int ct = 0; ct < 12; ++ct)
      sc[ct][i] = (sv[ct] > 0.0f) ? (sv[ct] - e0) * inv : 0.0f;
  }

#pragma unroll
  for (int i = 0; i < 4; ++i) {
    int r = 16 * w + 4 * hi + i;
#pragma unroll
    for (int ct = 0; ct < 12; ++ct)
      Ps[r * 200 + 16 * ct + lr] = f2bf(sc[ct][i]);
  }
  if (lr == 0) {
#pragma unroll
    for (int i = 0; i < 4; ++i) rowcoef[16 * w + 4 * hi + i] = rcv[i];
  }
  __syncthreads();

  U av[6];
#pragma unroll
  for (int ks = 0; ks < 6; ++ks) {
    int m8 = l0 - 64 + 32 * ks + 8 * hi;
    av[ks].i4 = make_int4(0, 0, 0, 0);
    if (m8 >= 0 && m8 < SEQLEN)
      av[ks].v = *(const s16x8*)(Vp + (size_t)(16 * w + lr) * SEQLEN + m8);
  }
  float vsv[4];
#pragma unroll
  for (int reg = 0; reg < 4; ++reg) vsv[reg] = vsum[vsbase + 16 * w + 4 * hi + reg];

  unsigned short* Ob = attnt + ((size_t)bz * SEQLEN) * 512 + hh * 64;
#pragma unroll
  for (int nt = 0; nt < 4; ++nt) {
    f32x4 acc = {0.f, 0.f, 0.f, 0.f};
#pragma unroll
    for (int ks = 0; ks < 6; ++ks) {
      s16x8 b = *(const s16x8*)&Ps[(16 * nt + lr) * 200 + 32 * ks + 8 * hi];
      acc = __builtin_amdgcn_mfma_f32_16x16x32_bf16(av[ks].v, b, acc, 0, 0, 0);
    }
    int l = l0 + 16 * nt + lr;
    float rcf = rowcoef[16 * nt + lr];
    ushort4 o = make_ushort4(f2bf(acc[0] + rcf * vsv[0]), f2bf(acc[1] + rcf * vsv[1]),
                             f2bf(acc[2] + rcf * vsv[2]), f2bf(acc[3] + rcf * vsv[3]));
    *(ushort4*)&Ob[(size_t)l * 512 + 16 * w + 4 * hi] = o;
  }
}

// ---------------- fused tail: LN1(Wc@attn + Wres@x) -> gelu(W1@..) -> LN2(W2@.. + res) ----------------
__global__ __launch_bounds__(256) void tail_k(const unsigned short* __restrict__ wcb,
                                              const unsigned short* __restrict__ wresb,
                                              const unsigned short* __restrict__ w1b,
                                              const unsigned short* __restrict__ w2b,
                                              const unsigned short* __restrict__ attnt,
                                              const unsigned short* __restrict__ xpt,
                                              const float* __restrict__ g1v,
                                              const float* __restrict__ b1v,
                                              const float* __restrict__ g2v,
                                              const float* __restrict__ b2v,
                                              float* __restrict__ outp) {
  __shared__ float gs1[64], bs1[64], gs2[64], bs2[64];
  __shared__ alignas(16) unsigned short pw[4][16][72];
  __shared__ alignas(16) unsigned short hw[4][16][264];

  int b = blockIdx.y;
  int l0 = blockIdx.x * 64;
  int t = threadIdx.x, w = t >> 6, lane = t & 63, lr = lane & 15, hi = lane >> 4;
  if (t < 64) { gs1[t] = g1v[t]; bs1[t] = b1v[t]; gs2[t] = g2v[t]; bs2[t] = b2v[t]; }
  __syncthreads();

  int lloc = 16 * w + lr;
  const unsigned short* brow = attnt + ((size_t)b * SEQLEN + l0 + lloc) * 512;
  const unsigned short* xrow = xpt + ((size_t)b * SEQLEN + l0 + lloc) * 512;

  // ---- phase 1: pred = LN1(Wc @ attnt + Wres @ x) ----
  f32x4 acc[4];
#pragma unroll
  for (int i = 0; i < 4; ++i) acc[i] = (f32x4){0.f, 0.f, 0.f, 0.f};
#pragma unroll
  for (int ks = 0; ks < 16; ++ks) {
    s16x8 bf = *(const s16x8*)(brow + 32 * ks + 8 * hi);
#pragma unroll
    for (int mt = 0; mt < 4; ++mt) {
      s16x8 af = *(const s16x8*)(wcb + (size_t)(16 * mt + lr) * 512 + 32 * ks + 8 * hi);
      acc[mt] = __builtin_amdgcn_mfma_f32_16x16x32_bf16(af, bf, acc[mt], 0, 0, 0);
    }
  }
#pragma unroll
  for (int ks = 0; ks < 8; ++ks) {
    s16x8 bf = *(const s16x8*)(xrow + 32 * ks + 8 * hi);
#pragma unroll
    for (int mt = 0; mt < 4; ++mt) {
      s16x8 af = *(const s16x8*)(wresb + (size_t)(16 * mt + lr) * 256 + 32 * ks + 8 * hi);
      acc[mt] = __builtin_amdgcn_mfma_f32_16x16x32_bf16(af, bf, acc[mt], 0, 0, 0);
    }
  }
  float resid[4][4];
  {
    float sum = 0.f, sq = 0.f;
#pragma unroll
    for (int mt = 0; mt < 4; ++mt)
#pragma unroll
      for (int reg = 0; reg < 4; ++reg) { float v = acc[mt][reg]; sum += v; sq += v * v; }
    sum += __shfl_xor(sum, 16, 64); sq += __shfl_xor(sq, 16, 64);
    sum += __shfl_xor(sum, 32, 64); sq += __shfl_xor(sq, 32, 64);
    float mu = sum * (1.0f / 64.0f);
    float var = sq * (1.0f / 64.0f) - mu * mu;
    float rstd = rsqrtf(var + 1e-5f);
#pragma unroll
    for (int mt = 0; mt < 4; ++mt) {
      float o[4];
#pragma unroll
      for (int reg = 0; reg < 4; ++reg) {
        int m = 16 * mt + 4 * hi + reg;
        o[reg] = (acc[mt][reg] - mu) * rstd * gs1[m] + bs1[m];
        resid[mt][reg] = o[reg];
      }
      *(ushort4*)&pw[w][lr][16 * mt + 4 * hi] =
          make_ushort4(f2bf(o[0]), f2bf(o[1]), f2bf(o[2]), f2bf(o[3]));
    }
  }
  __syncthreads();

  // ---- phase 2: h = gelu(W1 @ pred) ----
  {
    s16x8 bf0 = *(const s16x8*)&pw[w][lr][8 * hi];
    s16x8 bf1 = *(const s16x8*)&pw[w][lr][32 + 8 * hi];
#pragma unroll
    for (int mt = 0; mt < 16; ++mt) {
      s16x8 a0 = *(const s16x8*)(w1b + (size_t)(16 * mt + lr) * 64 + 8 * hi);
      s16x8 a1 = *(const s16x8*)(w1b + (size_t)(16 * mt + lr) * 64 + 32 + 8 * hi);
      f32x4 a2 = {0.f, 0.f, 0.f, 0.f};
      a2 = __builtin_amdgcn_mfma_f32_16x16x32_bf16(a0, bf0, a2, 0, 0, 0);
      a2 = __builtin_amdgcn_mfma_f32_16x16x32_bf16(a1, bf1, a2, 0, 0, 0);
      float v0 = a2[0], v1 = a2[1], v2 = a2[2], v3 = a2[3];
      v0 = 0.5f * v0 * (1.0f + erff(v0 * 0.70710678118654752440f));
      v1 = 0.5f * v1 * (1.0f + erff(v1 * 0.70710678118654752440f));
      v2 = 0.5f * v2 * (1.0f + erff(v2 * 0.70710678118654752440f));
      v3 = 0.5f * v3 * (1.0f + erff(v3 * 0.70710678118654752440f));
      *(ushort4*)&hw[w][lr][16 * mt + 4 * hi] = make_ushort4(f2bf(v0), f2bf(v1), f2bf(v2), f2bf(v3));
    }
  }
  __syncthreads();

  // ---- phase 3: out = LN2(W2 @ h + pred) ----
  f32x4 acc3[4];
#pragma unroll
  for (int i = 0; i < 4; ++i) acc3[i] = (f32x4){0.f, 0.f, 0.f, 0.f};
#pragma unroll
  for (int ks = 0; ks < 8; ++ks) {
    s16x8 bf = *(const s16x8*)&hw[w][lr][32 * ks + 8 * hi];
#pragma unroll
    for (int mt = 0; mt < 4; ++mt) {
      s16x8 af = *(const s16x8*)(w2b + (size_t)(16 * mt + lr) * 256 + 32 * ks + 8 * hi);
      acc3[mt] = __builtin_amdgcn_mfma_f32_16x16x32_bf16(af, bf, acc3[mt], 0, 0, 0);
    }
  }
#pragma unroll
  for (int mt = 0; mt < 4; ++mt)
#pragma unroll
    for (int reg = 0; reg < 4; ++reg) acc3[mt][reg] += resid[mt][reg];
  float sum = 0.f, sq = 0.f;
#pragma unroll
  for (int mt = 0; mt < 4; ++mt)
#pragma unroll
    for (int reg = 0; reg < 4; ++reg) { float v = acc3[mt][reg]; sum += v; sq += v * v; }
  sum += __shfl_xor(sum, 16, 64); sq += __shfl_xor(sq, 16, 64);
  sum += __shfl_xor(sum, 32, 64); sq += __shfl_xor(sq, 32, 64);
  float mu = sum * (1.0f / 64.0f);
  float var = sq * (1.0f / 64.0f) - mu * mu;
  float rstd = rsqrtf(var + 1e-5f);
  float* ob = outp + (size_t)b * 64 * SEQLEN;
  int l = l0 + lloc;
#pragma unroll
  for (int mt = 0; mt < 4; ++mt)
#pragma unroll
    for (int reg = 0; reg < 4; ++reg) {
      int m = 16 * mt + 4 * hi + reg;
      ob[(size_t)m * SEQLEN + l] = (acc3[mt][reg] - mu) * rstd * gs2[m] + bs2[m];
    }
}

extern "C" void kernel_launch(void* const* d_in, const int* in_sizes, int n_in,
                              void* d_out, int out_size, void* d_ws, size_t ws_size,
                              hipStream_t stream) {
  const float* x    = (const float*)d_in[0];
  const float* Wq   = (const float*)d_in[1];
  const float* Wk   = (const float*)d_in[2];
  const float* Wv   = (const float*)d_in[3];
  const float* Wres = (const float*)d_in[4];
  const float* Wc   = (const float*)d_in[5];
  const float* ln1g = (const float*)d_in[6];
  const float* ln1b = (const float*)d_in[7];
  const float* W1   = (const float*)d_in[8];
  const float* W2   = (const float*)d_in[9];
  const float* ln2g = (const float*)d_in[10];
  const float* ln2b = (const float*)d_in[11];

  char* base = (char*)d_ws;
  unsigned short* xpt   = (unsigned short*)base; base += (size_t)2097152 * 2;
  unsigned short* wqb   = (unsigned short*)base; base += (size_t)262144 * 2;
  unsigned short* wkb   = (unsigned short*)base; base += (size_t)262144 * 2;
  unsigned short* wvb   = (unsigned short*)base; base += (size_t)262144 * 2;
  unsigned short* wcb   = (unsigned short*)base; base += (size_t)32768 * 2;
  unsigned short* wresb = (unsigned short*)base; base += (size_t)16384 * 2;
  unsigned short* w1b   = (unsigned short*)base; base += (size_t)16384 * 2;
  unsigned short* w2b   = (unsigned short*)base; base += (size_t)16384 * 2;
  unsigned short* qt    = (unsigned short*)base; base += (size_t)2097152 * 2;
  unsigned short* kt    = (unsigned short*)base; base += (size_t)2097152 * 2;
  unsigned short* vbb   = (unsigned short*)base; base += (size_t)2097152 * 2;
  float* vsum           = (float*)base;          base += (size_t)1024 * 4;
  unsigned short* attnt = (unsigned short*)base; base += (size_t)2097152 * 2;
  float* outp = (float*)d_out;

  prep_k<<<1361, 256, 0, stream>>>(x, Wq, Wk, Wv, Wc, Wres, W1, W2,
                                   xpt, wqb, wkb, wvb, wcb, wresb, w1b, w2b, vsum);
  qkv_gemm_k<<<dim3(16, 24, NBATCH), 256, 0, stream>>>(wqb, wkb, wvb, xpt, qt, kt, vbb, vsum);
  attn_k<<<dim3(32, NH, NBATCH), 256, 0, stream>>>(qt, kt, vbb, vsum, attnt);
  tail_k<<<dim3(32, NBATCH), 256, 0, stream>>>(wcb, wresb, w1b, w2b, attnt, xpt,
                                               ln1g, ln1b, ln2g, ln2b, outp);
}

// Round 7
// 80.201 us; speedup vs baseline: 1.3588x; 1.0001x over previous
//
#include <hip/hip_runtime.h>
#include <cstdint>
#include <cstddef>

// ---- problem constants ----
#define SEQLEN 2048
#define NBATCH 2
#define NIND   256
#define NPOS   256
#define NCIN   512
#define NH     8
#define NDE    64
#define NDV    64
#define NREC   64

typedef __attribute__((ext_vector_type(8))) short s16x8;
typedef __attribute__((ext_vector_type(4))) float f32x4;

__device__ __forceinline__ unsigned short f2bf(float f) {
  union { float f; unsigned u; } v; v.f = f;
  unsigned r = v.u + 0x7fffu + ((v.u >> 16) & 1u);
  return (unsigned short)(r >> 16);
}

// async global->LDS, 16B per lane; LDS dest = wave-uniform base + lane*16
__device__ __forceinline__ void gload16(const unsigned short* g, unsigned short* l) {
  __builtin_amdgcn_global_load_lds(
      (const __attribute__((address_space(1))) unsigned int*)g,
      (__attribute__((address_space(3))) unsigned int*)l, 16, 0, 0);
}

// ---------------- prep: concat+pos transpose, all weight cvts, vsum zero ----------------
__global__ __launch_bounds__(256) void prep_k(const float* __restrict__ x,
                                              const float* __restrict__ Wq,
                                              const float* __restrict__ Wk,
                                              const float* __restrict__ Wv,
                                              const float* __restrict__ Wc,
                                              const float* __restrict__ Wres,
                                              const float* __restrict__ W1,
                                              const float* __restrict__ W2,
                                              unsigned short* __restrict__ xpt,
                                              unsigned short* __restrict__ wqb,
                                              unsigned short* __restrict__ wkb,
                                              unsigned short* __restrict__ wvb,
                                              unsigned short* __restrict__ wcb,
                                              unsigned short* __restrict__ wresb,
                                              unsigned short* __restrict__ w1b,
                                              unsigned short* __restrict__ w2b,
                                              float* __restrict__ vsum) {
  __shared__ float tile[64][65];
  int blk = blockIdx.x;
  int t = threadIdx.x;
  if (blk < 512) {
    int b = blk >> 8, c0 = ((blk >> 5) & 7) * 64, l0 = (blk & 31) * 64;
    if (c0 < NIND) {
      const float* src = x + ((size_t)b * NIND + c0) * SEQLEN;
      int ll = t & 63, cq = t >> 6;
#pragma unroll
      for (int i = 0; i < 16; ++i) {
        int cl = cq * 16 + i;
        tile[cl][ll] = src[(size_t)cl * SEQLEN + l0 + ll];
      }
      __syncthreads();
      int cl2 = t & 63, lq = t >> 6;
      unsigned short* dst = xpt + ((size_t)b * SEQLEN + l0) * NCIN + c0;
#pragma unroll
      for (int i = 0; i < 16; ++i) {
        int l = lq * 16 + i;
        dst[(size_t)l * NCIN + cl2] = f2bf(tile[cl2][l]);
      }
    } else {
      int c = c0 + (t & 63);
      int j = c - NIND;
      int i = (j < NPOS / 2) ? j : j - NPOS / 2;
      const double base = (double)1.2f;
      double p = 1.0;
      for (int tt = 0; tt <= i; ++tt) p *= base;
      float w = 0.8f + (float)p;
      float swl = (float)SEQLEN / w;
      const float two_pi = (float)(2.0 * 3.14159265358979323846);
      int wv = t >> 6;
      unsigned short* dst = xpt + (size_t)b * SEQLEN * NCIN;
#pragma unroll
      for (int it = 0; it < 16; ++it) {
        int l = l0 + 16 * wv + it;
        float arg = (two_pi * (float)l) / swl;
        float val = (j < NPOS / 2) ? sinf(arg) : cosf(arg);
        dst[(size_t)l * NCIN + c] = f2bf(val);
      }
    }
  } else if (blk == 1360) {
    ((float4*)vsum)[t] = make_float4(0.f, 0.f, 0.f, 0.f);
  } else {
    const float* in;
    unsigned short* out;
    int idx4;
    if (blk < 1280) {
      int i = (blk - 512) * 256 + t;
      int which = i >> 16;
      idx4 = i & 65535;
      in = (which == 0) ? Wq : ((which == 1) ? Wk : Wv);
      out = (which == 0) ? wqb : ((which == 1) ? wkb : wvb);
    } else if (blk < 1312) { in = Wc;   out = wcb;   idx4 = (blk - 1280) * 256 + t; }
    else if (blk < 1328)   { in = Wres; out = wresb; idx4 = (blk - 1312) * 256 + t; }
    else if (blk < 1344)   { in = W1;   out = w1b;   idx4 = (blk - 1328) * 256 + t; }
    else                   { in = W2;   out = w2b;   idx4 = (blk - 1344) * 256 + t; }
    float4 v = ((const float4*)in)[idx4];
    ((ushort4*)out)[idx4] = make_ushort4(f2bf(v.x), f2bf(v.y), f2bf(v.z), f2bf(v.w));
  }
}

// ---------------- fused QKV MFMA GEMM: 64x128, BK=64, double-buffered gload_lds + swizzle ----------------
// 2-phase prefetch: STAGE(next) issued before COMPUTE(cur); one drain-barrier per K-step.
__global__ __launch_bounds__(256) void qkv_gemm_k(const unsigned short* __restrict__ Wqb,
                                                  const unsigned short* __restrict__ Wkb,
                                                  const unsigned short* __restrict__ Wvb,
                                                  const unsigned short* __restrict__ xpt,
                                                  unsigned short* __restrict__ qt,
                                                  unsigned short* __restrict__ kt,
                                                  unsigned short* __restrict__ vb,
                                                  float* __restrict__ vsum) {
  __shared__ alignas(16) unsigned short lds[24576];   // 2 x (A 64x64 | B 128x64)

  int bz = blockIdx.z;
  int y = blockIdx.y;
  int ysel = y >> 3;
  int m0 = (y & 7) * 64;
  int n0 = blockIdx.x * 128;
  const unsigned short* W = (ysel == 0) ? Wqb : ((ysel == 1) ? Wkb : Wvb);
  const unsigned short* Bg = xpt + (size_t)bz * SEQLEN * NCIN;

  int t = threadIdx.x;
  int w = t >> 6, lane = t & 63, lr = lane & 15, hi = lane >> 4;
  int wm = w >> 1, wn = w & 1;

  // staging: lane -> (row-in-8-group sr, chunk); source chunk pre-swizzled by sr
  int sr = lane >> 3;
  int scs = ((lane & 7) ^ sr) * 8;   // shorts
  const unsigned short* gA0 = W  + (size_t)(m0 + 16 * w + sr) * 512 + scs;
  const unsigned short* gB0 = Bg + (size_t)(n0 + 32 * w + sr) * 512 + scs;

  int swz = (lr & 7) << 3;           // read-side XOR (shorts)

  f32x4 acc[2][4];
#pragma unroll
  for (int i = 0; i < 2; ++i)
#pragma unroll
    for (int j = 0; j < 4; ++j) acc[i][j] = (f32x4){0.f, 0.f, 0.f, 0.f};

  auto stage = [&](int buf, int k0) {
    unsigned short* Ad = lds + buf * 12288 + (16 * w) * 64;
    unsigned short* Bd = lds + buf * 12288 + 4096 + (32 * w) * 64;
    gload16(gA0 + k0,            Ad);
    gload16(gA0 + k0 + 8 * 512,  Ad + 8 * 64);
    gload16(gB0 + k0,            Bd);
    gload16(gB0 + k0 + 8 * 512,  Bd + 8 * 64);
    gload16(gB0 + k0 + 16 * 512, Bd + 16 * 64);
    gload16(gB0 + k0 + 24 * 512, Bd + 24 * 64);
  };
  auto compute = [&](int buf) {
    const unsigned short* Ar = lds + buf * 12288;
    const unsigned short* Br = Ar + 4096;
#pragma unroll
    for (int ks = 0; ks < 2; ++ks) {
      s16x8 af[2], bfv[4];
#pragma unroll
      for (int mt = 0; mt < 2; ++mt)
        af[mt] = *(const s16x8*)&Ar[(32 * wm + 16 * mt + lr) * 64 + ((32 * ks + 8 * hi) ^ swz)];
#pragma unroll
      for (int nt = 0; nt < 4; ++nt)
        bfv[nt] = *(const s16x8*)&Br[(64 * wn + 16 * nt + lr) * 64 + ((32 * ks + 8 * hi) ^ swz)];
#pragma unroll
      for (int mt = 0; mt < 2; ++mt)
#pragma unroll
        for (int nt = 0; nt < 4; ++nt)
          acc[mt][nt] = __builtin_amdgcn_mfma_f32_16x16x32_bf16(af[mt], bfv[nt], acc[mt][nt], 0, 0, 0);
    }
  };

  stage(0, 0);
  __syncthreads();                       // drain prologue DMA
#pragma unroll
  for (int it = 0; it < 8; ++it) {
    if (it < 7) stage((it + 1) & 1, (it + 1) * 64);   // prefetch next K-step
    compute(it & 1);
    __syncthreads();                     // drain prefetch DMA + retire LDS reads
  }

  if (ysel == 2) {
    // vsum partial sums (over this block's 128 columns)
#pragma unroll
    for (int mt = 0; mt < 2; ++mt)
#pragma unroll
      for (int reg = 0; reg < 4; ++reg) {
        float p = acc[mt][0][reg] + acc[mt][1][reg] + acc[mt][2][reg] + acc[mt][3][reg];
        p += __shfl_xor(p, 1, 64);
        p += __shfl_xor(p, 2, 64);
        p += __shfl_xor(p, 4, 64);
        p += __shfl_xor(p, 8, 64);
        if (lr == 0)
          atomicAdd(&vsum[bz * 512 + m0 + 32 * wm + 16 * mt + 4 * hi + reg], p);
      }
  }

  if (ysel < 2) {
    // stage Cl[l 128][d 64] pitch 68, then coalesced 128B-row stores
    unsigned short* Cl = lds;
#pragma unroll
    for (int mt = 0; mt < 2; ++mt)
#pragma unroll
      for (int nt = 0; nt < 4; ++nt) {
        int lloc = 64 * wn + 16 * nt + lr;
        int d0 = 32 * wm + 16 * mt + 4 * hi;
        *(ushort4*)&Cl[lloc * 68 + d0] = make_ushort4(f2bf(acc[mt][nt][0]), f2bf(acc[mt][nt][1]),
                                                      f2bf(acc[mt][nt][2]), f2bf(acc[mt][nt][3]));
      }
    __syncthreads();
    int h = m0 >> 6;
    unsigned short* Cb = ((ysel == 0) ? qt : kt) + ((size_t)(bz * NH + h) * SEQLEN + n0) * 64;
    int rr = t >> 1, cc = (t & 1) * 32;
#pragma unroll
    for (int j = 0; j < 4; ++j)
      *(int4*)&Cb[(size_t)rr * 64 + cc + 8 * j] = *(const int4*)&Cl[rr * 68 + cc + 8 * j];
  } else {
    // stage Cl2[d 64][l 128] pitch 132, then coalesced 256B-row stores
    unsigned short* Cl2 = lds;
#pragma unroll
    for (int mt = 0; mt < 2; ++mt)
#pragma unroll
      for (int nt = 0; nt < 4; ++nt) {
        int lloc = 64 * wn + 16 * nt + lr;
#pragma unroll
        for (int reg = 0; reg < 4; ++reg)
          Cl2[(32 * wm + 16 * mt + 4 * hi + reg) * 132 + lloc] = f2bf(acc[mt][nt][reg]);
      }
    __syncthreads();
    int dd = t >> 2, cc = (t & 3) * 32;
    unsigned short* Vb = vb + ((size_t)(bz * 512 + m0 + dd)) * SEQLEN + n0;
#pragma unroll
    for (int j = 0; j < 4; ++j)
      *(int4*)&Vb[cc + 8 * j] = *(const int4*)&Cl2[dd * 132 + cc + 8 * j];
  }
}

// ---------------- banded attention, MFMA, unconditional direct-global fragments ----------------
// Out-of-range m columns are provably masked (ib=false -> excluded from max/Z, P=0),
// and all overrun addresses stay inside d_ws (finite bf16 garbage is safe).
__global__ __launch_bounds__(256) void attn_k(const unsigned short* __restrict__ qt,
                                              const unsigned short* __restrict__ kt,
                                              const unsigned short* __restrict__ vb,
                                              const float* __restrict__ vsum,
                                              unsigned short* __restrict__ attnt) {
  __shared__ alignas(16) unsigned short Ps[64 * 200];
  __shared__ float rowcoef[64];

  int bz = blockIdx.z, hh = blockIdx.y;
  int l0 = blockIdx.x * 64;
  int bh = bz * NH + hh;
  const unsigned short* Qb = qt + (size_t)bh * SEQLEN * 64;
  const unsigned short* Kb = kt + (size_t)bh * SEQLEN * 64;
  const unsigned short* Vp = vb + (size_t)(bz * 512 + hh * 64) * SEQLEN;
  int vsbase = bz * 512 + hh * 64;

  int t = threadIdx.x;
  int w = t >> 6, lane = t & 63, lr = lane & 15, hi = lane >> 4;

  s16x8 a0 = *(const s16x8*)(Qb + ((size_t)(l0 + 16 * w + lr)) * 64 + 8 * hi);
  s16x8 a1 = *(const s16x8*)(Qb + ((size_t)(l0 + 16 * w + lr)) * 64 + 32 + 8 * hi);

  f32x4 sc[12];
#pragma unroll
  for (int ct = 0; ct < 12; ++ct) {
    int m = l0 - 64 + 16 * ct + lr;
    const unsigned short* kp = Kb + (ptrdiff_t)m * 64;
    s16x8 b0 = *(const s16x8*)(kp + 8 * hi);
    s16x8 b1 = *(const s16x8*)(kp + 32 + 8 * hi);
    f32x4 acc = {0.f, 0.f, 0.f, 0.f};
    acc = __builtin_amdgcn_mfma_f32_16x16x32_bf16(a0, b0, acc, 0, 0, 0);
    acc = __builtin_amdgcn_mfma_f32_16x16x32_bf16(a1, b1, acc, 0, 0, 0);
    sc[ct] = acc;
  }

  float rcv[4];
#pragma unroll
  for (int i = 0; i < 4; ++i) {
    int r = 16 * w + 4 * hi + i;
    int l = l0 + r;
    float mx = 0.0f;
    float sv[12];
#pragma unroll
    for (int ct = 0; ct < 12; ++ct) {
      int c = 16 * ct + lr;
      int m = l0 - 64 + c;
      bool ib = (c >= r) && (c <= r + 128) && (m >= 0) && (m < SEQLEN);
      float s = sc[ct][i] * 0.125f;
      sv[ct] = ib ? s : -1e30f;
      mx = ib ? fmaxf(mx, s) : mx;
    }
    mx = fmaxf(mx, __shfl_xor(mx, 1, 64));
    mx = fmaxf(mx, __shfl_xor(mx, 2, 64));
    mx = fmaxf(mx, __shfl_xor(mx, 4, 64));
    mx = fmaxf(mx, __shfl_xor(mx, 8, 64));
    float e0 = expf(-mx);
    float zs = 0.f;
#pragma unroll
    for (int ct = 0; ct < 12; ++ct) {
      float e = (sv[ct] > -1e29f) ? expf(sv[ct] - mx) : 0.0f;
      sv[ct] = e;
      zs += e;
    }
    zs += __shfl_xor(zs, 1, 64);
    zs += __shfl_xor(zs, 2, 64);
    zs += __shfl_xor(zs, 4, 64);
    zs += __shfl_xor(zs, 8, 64);
    int lo = l - NREC; if (lo < 0) lo = 0;
    int hi2 = l + NREC; if (hi2 > SEQLEN - 1) hi2 = SEQLEN - 1;
    float inv = 1.0f / (zs + (float)(SEQLEN - (hi2 - lo + 1)) * e0);
    rcv[i] = e0 * inv;
#pragma unroll
    for (int ct = 0; ct < 12; ++ct)
      sc[ct][i] = (sv[ct] > 0.0f) ? (sv[ct] - e0) * inv : 0.0f;
  }

#pragma unroll
  for (int i = 0; i < 4; ++i) {
    int r = 16 * w + 4 * hi + i;
#pragma unroll
    for (int ct = 0; ct < 12; ++ct)
      Ps[r * 200 + 16 * ct + lr] = f2bf(sc[ct][i]);
  }
  if (lr == 0) {
#pragma unroll
    for (int i = 0; i < 4; ++i) rowcoef[16 * w + 4 * hi + i] = rcv[i];
  }
  __syncthreads();

  s16x8 av[6];
#pragma unroll
  for (int ks = 0; ks < 6; ++ks) {
    int m8 = l0 - 64 + 32 * ks + 8 * hi;
    av[ks] = *(const s16x8*)(Vp + (ptrdiff_t)(16 * w + lr) * SEQLEN + m8);
  }
  float vsv[4];
#pragma unroll
  for (int reg = 0; reg < 4; ++reg) vsv[reg] = vsum[vsbase + 16 * w + 4 * hi + reg];

  unsigned short* Ob = attnt + ((size_t)bz * SEQLEN) * 512 + hh * 64;
#pragma unroll
  for (int nt = 0; nt < 4; ++nt) {
    f32x4 acc = {0.f, 0.f, 0.f, 0.f};
#pragma unroll
    for (int ks = 0; ks < 6; ++ks) {
      s16x8 b = *(const s16x8*)&Ps[(16 * nt + lr) * 200 + 32 * ks + 8 * hi];
      acc = __builtin_amdgcn_mfma_f32_16x16x32_bf16(av[ks], b, acc, 0, 0, 0);
    }
    int l = l0 + 16 * nt + lr;
    float rcf = rowcoef[16 * nt + lr];
    ushort4 o = make_ushort4(f2bf(acc[0] + rcf * vsv[0]), f2bf(acc[1] + rcf * vsv[1]),
                             f2bf(acc[2] + rcf * vsv[2]), f2bf(acc[3] + rcf * vsv[3]));
    *(ushort4*)&Ob[(size_t)l * 512 + 16 * w + 4 * hi] = o;
  }
}

// ---------------- fused tail: LN1(Wc@attn + Wres@x) -> gelu(W1@..) -> LN2(W2@.. + res) ----------------
__global__ __launch_bounds__(256) void tail_k(const unsigned short* __restrict__ wcb,
                                              const unsigned short* __restrict__ wresb,
                                              const unsigned short* __restrict__ w1b,
                                              const unsigned short* __restrict__ w2b,
                                              const unsigned short* __restrict__ attnt,
                                              const unsigned short* __restrict__ xpt,
                                              const float* __restrict__ g1v,
                                              const float* __restrict__ b1v,
                                              const float* __restrict__ g2v,
                                              const float* __restrict__ b2v,
                                              float* __restrict__ outp) {
  __shared__ float gs1[64], bs1[64], gs2[64], bs2[64];
  __shared__ alignas(16) unsigned short pw[4][16][72];
  __shared__ alignas(16) unsigned short hw[4][16][264];

  int b = blockIdx.y;
  int l0 = blockIdx.x * 64;
  int t = threadIdx.x, w = t >> 6, lane = t & 63, lr = lane & 15, hi = lane >> 4;
  if (t < 64) { gs1[t] = g1v[t]; bs1[t] = b1v[t]; gs2[t] = g2v[t]; bs2[t] = b2v[t]; }
  __syncthreads();

  int lloc = 16 * w + lr;
  const unsigned short* brow = attnt + ((size_t)b * SEQLEN + l0 + lloc) * 512;
  const unsigned short* xrow = xpt + ((size_t)b * SEQLEN + l0 + lloc) * 512;

  // ---- phase 1: pred = LN1(Wc @ attnt + Wres @ x) ----
  f32x4 acc[4];
#pragma unroll
  for (int i = 0; i < 4; ++i) acc[i] = (f32x4){0.f, 0.f, 0.f, 0.f};
#pragma unroll
  for (int ks = 0; ks < 16; ++ks) {
    s16x8 bf = *(const s16x8*)(brow + 32 * ks + 8 * hi);
#pragma unroll
    for (int mt = 0; mt < 4; ++mt) {
      s16x8 af = *(const s16x8*)(wcb + (size_t)(16 * mt + lr) * 512 + 32 * ks + 8 * hi);
      acc[mt] = __builtin_amdgcn_mfma_f32_16x16x32_bf16(af, bf, acc[mt], 0, 0, 0);
    }
  }
#pragma unroll
  for (int ks = 0; ks < 8; ++ks) {
    s16x8 bf = *(const s16x8*)(xrow + 32 * ks + 8 * hi);
#pragma unroll
    for (int mt = 0; mt < 4; ++mt) {
      s16x8 af = *(const s16x8*)(wresb + (size_t)(16 * mt + lr) * 256 + 32 * ks + 8 * hi);
      acc[mt] = __builtin_amdgcn_mfma_f32_16x16x32_bf16(af, bf, acc[mt], 0, 0, 0);
    }
  }
  float resid[4][4];
  {
    float sum = 0.f, sq = 0.f;
#pragma unroll
    for (int mt = 0; mt < 4; ++mt)
#pragma unroll
      for (int reg = 0; reg < 4; ++reg) { float v = acc[mt][reg]; sum += v; sq += v * v; }
    sum += __shfl_xor(sum, 16, 64); sq += __shfl_xor(sq, 16, 64);
    sum += __shfl_xor(sum, 32, 64); sq += __shfl_xor(sq, 32, 64);
    float mu = sum * (1.0f / 64.0f);
    float var = sq * (1.0f / 64.0f) - mu * mu;
    float rstd = rsqrtf(var + 1e-5f);
#pragma unroll
    for (int mt = 0; mt < 4; ++mt) {
      float o[4];
#pragma unroll
      for (int reg = 0; reg < 4; ++reg) {
        int m = 16 * mt + 4 * hi + reg;
        o[reg] = (acc[mt][reg] - mu) * rstd * gs1[m] + bs1[m];
        resid[mt][reg] = o[reg];
      }
      *(ushort4*)&pw[w][lr][16 * mt + 4 * hi] =
          make_ushort4(f2bf(o[0]), f2bf(o[1]), f2bf(o[2]), f2bf(o[3]));
    }
  }
  __syncthreads();

  // ---- phase 2: h = gelu(W1 @ pred) ----
  {
    s16x8 bf0 = *(const s16x8*)&pw[w][lr][8 * hi];
    s16x8 bf1 = *(const s16x8*)&pw[w][lr][32 + 8 * hi];
#pragma unroll
    for (int mt = 0; mt < 16; ++mt) {
      s16x8 a0 = *(const s16x8*)(w1b + (size_t)(16 * mt + lr) * 64 + 8 * hi);
      s16x8 a1 = *(const s16x8*)(w1b + (size_t)(16 * mt + lr) * 64 + 32 + 8 * hi);
      f32x4 a2 = {0.f, 0.f, 0.f, 0.f};
      a2 = __builtin_amdgcn_mfma_f32_16x16x32_bf16(a0, bf0, a2, 0, 0, 0);
      a2 = __builtin_amdgcn_mfma_f32_16x16x32_bf16(a1, bf1, a2, 0, 0, 0);
      float v0 = a2[0], v1 = a2[1], v2 = a2[2], v3 = a2[3];
      v0 = 0.5f * v0 * (1.0f + erff(v0 * 0.70710678118654752440f));
      v1 = 0.5f * v1 * (1.0f + erff(v1 * 0.70710678118654752440f));
      v2 = 0.5f * v2 * (1.0f + erff(v2 * 0.70710678118654752440f));
      v3 = 0.5f * v3 * (1.0f + erff(v3 * 0.70710678118654752440f));
      *(ushort4*)&hw[w][lr][16 * mt + 4 * hi] = make_ushort4(f2bf(v0), f2bf(v1), f2bf(v2), f2bf(v3));
    }
  }
  __syncthreads();

  // ---- phase 3: out = LN2(W2 @ h + pred) ----
  f32x4 acc3[4];
#pragma unroll
  for (int i = 0; i < 4; ++i) acc3[i] = (f32x4){0.f, 0.f, 0.f, 0.f};
#pragma unroll
  for (int ks = 0; ks < 8; ++ks) {
    s16x8 bf = *(const s16x8*)&hw[w][lr][32 * ks + 8 * hi];
#pragma unroll
    for (int mt = 0; mt < 4; ++mt) {
      s16x8 af = *(const s16x8*)(w2b + (size_t)(16 * mt + lr) * 256 + 32 * ks + 8 * hi);
      acc3[mt] = __builtin_amdgcn_mfma_f32_16x16x32_bf16(af, bf, acc3[mt], 0, 0, 0);
    }
  }
#pragma unroll
  for (int mt = 0; mt < 4; ++mt)
#pragma unroll
    for (int reg = 0; reg < 4; ++reg) acc3[mt][reg] += resid[mt][reg];
  float sum = 0.f, sq = 0.f;
#pragma unroll
  for (int mt = 0; mt < 4; ++mt)
#pragma unroll
    for (int reg = 0; reg < 4; ++reg) { float v = acc3[mt][reg]; sum += v; sq += v * v; }
  sum += __shfl_xor(sum, 16, 64); sq += __shfl_xor(sq, 16, 64);
  sum += __shfl_xor(sum, 32, 64); sq += __shfl_xor(sq, 32, 64);
  float mu = sum * (1.0f / 64.0f);
  float var = sq * (1.0f / 64.0f) - mu * mu;
  float rstd = rsqrtf(var + 1e-5f);
  float* ob = outp + (size_t)b * 64 * SEQLEN;
  int l = l0 + lloc;
#pragma unroll
  for (int mt = 0; mt < 4; ++mt)
#pragma unroll
    for (int reg = 0; reg < 4; ++reg) {
      int m = 16 * mt + 4 * hi + reg;
      ob[(size_t)m * SEQLEN + l] = (acc3[mt][reg] - mu) * rstd * gs2[m] + bs2[m];
    }
}

extern "C" void kernel_launch(void* const* d_in, const int* in_sizes, int n_in,
                              void* d_out, int out_size, void* d_ws, size_t ws_size,
                              hipStream_t stream) {
  const float* x    = (const float*)d_in[0];
  const float* Wq   = (const float*)d_in[1];
  const float* Wk   = (const float*)d_in[2];
  const float* Wv   = (const float*)d_in[3];
  const float* Wres = (const float*)d_in[4];
  const float* Wc   = (const float*)d_in[5];
  const float* ln1g = (const float*)d_in[6];
  const float* ln1b = (const float*)d_in[7];
  const float* W1   = (const float*)d_in[8];
  const float* W2   = (const float*)d_in[9];
  const float* ln2g = (const float*)d_in[10];
  const float* ln2b = (const float*)d_in[11];

  char* base = (char*)d_ws;
  unsigned short* xpt   = (unsigned short*)base; base += (size_t)2097152 * 2;
  unsigned short* wqb   = (unsigned short*)base; base += (size_t)262144 * 2;
  unsigned short* wkb   = (unsigned short*)base; base += (size_t)262144 * 2;
  unsigned short* wvb   = (unsigned short*)base; base += (size_t)262144 * 2;
  unsigned short* wcb   = (unsigned short*)base; base += (size_t)32768 * 2;
  unsigned short* wresb = (unsigned short*)base; base += (size_t)16384 * 2;
  unsigned short* w1b   = (unsigned short*)base; base += (size_t)16384 * 2;
  unsigned short* w2b   = (unsigned short*)base; base += (size_t)16384 * 2;
  unsigned short* qt    = (unsigned short*)base; base += (size_t)2097152 * 2;
  unsigned short* kt    = (unsigned short*)base; base += (size_t)2097152 * 2;
  unsigned short* vbb   = (unsigned short*)base; base += (size_t)2097152 * 2;
  float* vsum           = (float*)base;          base += (size_t)1024 * 4;
  unsigned short* attnt = (unsigned short*)base; base += (size_t)2097152 * 2;
  float* outp = (float*)d_out;

  prep_k<<<1361, 256, 0, stream>>>(x, Wq, Wk, Wv, Wc, Wres, W1, W2,
                                   xpt, wqb, wkb, wvb, wcb, wresb, w1b, w2b, vsum);
  qkv_gemm_k<<<dim3(16, 24, NBATCH), 256, 0, stream>>>(wqb, wkb, wvb, xpt, qt, kt, vbb, vsum);
  attn_k<<<dim3(32, NH, NBATCH), 256, 0, stream>>>(qt, kt, vbb, vsum, attnt);
  tail_k<<<dim3(32, NBATCH), 256, 0, stream>>>(wcb, wresb, w1b, w2b, attnt, xpt,
                                               ln1g, ln1b, ln2g, ln2b, outp);
}

// Round 10
// 71.576 us; speedup vs baseline: 1.5225x; 1.1205x over previous
//
#include <hip/hip_runtime.h>
#include <cstdint>
#include <cstddef>

// ---- problem constants ----
#define SEQLEN 2048
#define NBATCH 2
#define NIND   256
#define NPOS   256
#define NCIN   512
#define NH     8
#define NDE    64
#define NDV    64
#define NREC   64

typedef __attribute__((ext_vector_type(8))) short s16x8;
typedef __attribute__((ext_vector_type(4))) float f32x4;

__device__ __forceinline__ unsigned short f2bf(float f) {
  union { float f; unsigned u; } v; v.f = f;
  unsigned r = v.u + 0x7fffu + ((v.u >> 16) & 1u);
  return (unsigned short)(r >> 16);
}

// async global->LDS, 16B per lane; LDS dest = wave-uniform base + lane*16
__device__ __forceinline__ void gload16(const unsigned short* g, unsigned short* l) {
  __builtin_amdgcn_global_load_lds(
      (const __attribute__((address_space(1))) unsigned int*)g,
      (__attribute__((address_space(3))) unsigned int*)l, 16, 0, 0);
}

// ---------------- prep: concat+pos transpose, all weight cvts, vsum zero ----------------
__global__ __launch_bounds__(256) void prep_k(const float* __restrict__ x,
                                              const float* __restrict__ Wq,
                                              const float* __restrict__ Wk,
                                              const float* __restrict__ Wv,
                                              const float* __restrict__ Wc,
                                              const float* __restrict__ Wres,
                                              const float* __restrict__ W1,
                                              const float* __restrict__ W2,
                                              unsigned short* __restrict__ xpt,
                                              unsigned short* __restrict__ wqb,
                                              unsigned short* __restrict__ wkb,
                                              unsigned short* __restrict__ wvb,
                                              unsigned short* __restrict__ wcb,
                                              unsigned short* __restrict__ wresb,
                                              unsigned short* __restrict__ w1b,
                                              unsigned short* __restrict__ w2b,
                                              float* __restrict__ vsum) {
  __shared__ float tile[64][65];
  int blk = blockIdx.x;
  int t = threadIdx.x;
  if (blk < 512) {
    int b = blk >> 8, c0 = ((blk >> 5) & 7) * 64, l0 = (blk & 31) * 64;
    if (c0 < NIND) {
      const float* src = x + ((size_t)b * NIND + c0) * SEQLEN;
      int ll = t & 63, cq = t >> 6;
#pragma unroll
      for (int i = 0; i < 16; ++i) {
        int cl = cq * 16 + i;
        tile[cl][ll] = src[(size_t)cl * SEQLEN + l0 + ll];
      }
      __syncthreads();
      int cl2 = t & 63, lq = t >> 6;
      unsigned short* dst = xpt + ((size_t)b * SEQLEN + l0) * NCIN + c0;
#pragma unroll
      for (int i = 0; i < 16; ++i) {
        int l = lq * 16 + i;
        dst[(size_t)l * NCIN + cl2] = f2bf(tile[cl2][l]);
      }
    } else {
      int c = c0 + (t & 63);
      int j = c - NIND;
      int i = (j < NPOS / 2) ? j : j - NPOS / 2;
      const double base = (double)1.2f;
      double p = 1.0;
      for (int tt = 0; tt <= i; ++tt) p *= base;
      float w = 0.8f + (float)p;
      float swl = (float)SEQLEN / w;
      const float two_pi = (float)(2.0 * 3.14159265358979323846);
      int wv = t >> 6;
      unsigned short* dst = xpt + (size_t)b * SEQLEN * NCIN;
#pragma unroll
      for (int it = 0; it < 16; ++it) {
        int l = l0 + 16 * wv + it;
        float arg = (two_pi * (float)l) / swl;
        float val = (j < NPOS / 2) ? sinf(arg) : cosf(arg);
        dst[(size_t)l * NCIN + c] = f2bf(val);
      }
    }
  } else if (blk == 1360) {
    ((float4*)vsum)[t] = make_float4(0.f, 0.f, 0.f, 0.f);
  } else {
    const float* in;
    unsigned short* out;
    int idx4;
    if (blk < 1280) {
      int i = (blk - 512) * 256 + t;
      int which = i >> 16;
      idx4 = i & 65535;
      in = (which == 0) ? Wq : ((which == 1) ? Wk : Wv);
      out = (which == 0) ? wqb : ((which == 1) ? wkb : wvb);
    } else if (blk < 1312) { in = Wc;   out = wcb;   idx4 = (blk - 1280) * 256 + t; }
    else if (blk < 1328)   { in = Wres; out = wresb; idx4 = (blk - 1312) * 256 + t; }
    else if (blk < 1344)   { in = W1;   out = w1b;   idx4 = (blk - 1328) * 256 + t; }
    else                   { in = W2;   out = w2b;   idx4 = (blk - 1344) * 256 + t; }
    float4 v = ((const float4*)in)[idx4];
    ((ushort4*)out)[idx4] = make_ushort4(f2bf(v.x), f2bf(v.y), f2bf(v.z), f2bf(v.w));
  }
}

// ---------------- fused QKV MFMA GEMM: 64x128, BK=64, double-buffered gload_lds + swizzle ----------------
__global__ __launch_bounds__(256) void qkv_gemm_k(const unsigned short* __restrict__ Wqb,
                                                  const unsigned short* __restrict__ Wkb,
                                                  const unsigned short* __restrict__ Wvb,
                                                  const unsigned short* __restrict__ xpt,
                                                  unsigned short* __restrict__ qt,
                                                  unsigned short* __restrict__ kt,
                                                  unsigned short* __restrict__ vb,
                                                  float* __restrict__ vsum) {
  __shared__ alignas(16) unsigned short lds[24576];   // 2 x (A 64x64 | B 128x64)

  int bz = blockIdx.z;
  int y = blockIdx.y;
  int ysel = y >> 3;
  int m0 = (y & 7) * 64;
  int n0 = blockIdx.x * 128;
  const unsigned short* W = (ysel == 0) ? Wqb : ((ysel == 1) ? Wkb : Wvb);
  const unsigned short* Bg = xpt + (size_t)bz * SEQLEN * NCIN;

  int t = threadIdx.x;
  int w = t >> 6, lane = t & 63, lr = lane & 15, hi = lane >> 4;
  int wm = w >> 1, wn = w & 1;

  int sr = lane >> 3;
  int scs = ((lane & 7) ^ sr) * 8;   // shorts, source pre-swizzled by row
  const unsigned short* gA0 = W  + (size_t)(m0 + 16 * w + sr) * 512 + scs;
  const unsigned short* gB0 = Bg + (size_t)(n0 + 32 * w + sr) * 512 + scs;

  int swz = (lr & 7) << 3;           // read-side XOR (shorts)

  f32x4 acc[2][4];
#pragma unroll
  for (int i = 0; i < 2; ++i)
#pragma unroll
    for (int j = 0; j < 4; ++j) acc[i][j] = (f32x4){0.f, 0.f, 0.f, 0.f};

  auto stage = [&](int buf, int k0) {
    unsigned short* Ad = lds + buf * 12288 + (16 * w) * 64;
    unsigned short* Bd = lds + buf * 12288 + 4096 + (32 * w) * 64;
    gload16(gA0 + k0,            Ad);
    gload16(gA0 + k0 + 8 * 512,  Ad + 8 * 64);
    gload16(gB0 + k0,            Bd);
    gload16(gB0 + k0 + 8 * 512,  Bd + 8 * 64);
    gload16(gB0 + k0 + 16 * 512, Bd + 16 * 64);
    gload16(gB0 + k0 + 24 * 512, Bd + 24 * 64);
  };
  auto compute = [&](int buf) {
    const unsigned short* Ar = lds + buf * 12288;
    const unsigned short* Br = Ar + 4096;
#pragma unroll
    for (int ks = 0; ks < 2; ++ks) {
      s16x8 af[2], bfv[4];
#pragma unroll
      for (int mt = 0; mt < 2; ++mt)
        af[mt] = *(const s16x8*)&Ar[(32 * wm + 16 * mt + lr) * 64 + ((32 * ks + 8 * hi) ^ swz)];
#pragma unroll
      for (int nt = 0; nt < 4; ++nt)
        bfv[nt] = *(const s16x8*)&Br[(64 * wn + 16 * nt + lr) * 64 + ((32 * ks + 8 * hi) ^ swz)];
#pragma unroll
      for (int mt = 0; mt < 2; ++mt)
#pragma unroll
        for (int nt = 0; nt < 4; ++nt)
          acc[mt][nt] = __builtin_amdgcn_mfma_f32_16x16x32_bf16(af[mt], bfv[nt], acc[mt][nt], 0, 0, 0);
    }
  };

  stage(0, 0);
  __syncthreads();
#pragma unroll
  for (int it = 0; it < 8; ++it) {
    if (it < 7) stage((it + 1) & 1, (it + 1) * 64);
    compute(it & 1);
    __syncthreads();
  }

  if (ysel == 2) {
#pragma unroll
    for (int mt = 0; mt < 2; ++mt)
#pragma unroll
      for (int reg = 0; reg < 4; ++reg) {
        float p = acc[mt][0][reg] + acc[mt][1][reg] + acc[mt][2][reg] + acc[mt][3][reg];
        p += __shfl_xor(p, 1, 64);
        p += __shfl_xor(p, 2, 64);
        p += __shfl_xor(p, 4, 64);
        p += __shfl_xor(p, 8, 64);
        if (lr == 0)
          atomicAdd(&vsum[bz * 512 + m0 + 32 * wm + 16 * mt + 4 * hi + reg], p);
      }
  }

  if (ysel < 2) {
    unsigned short* Cl = lds;
#pragma unroll
    for (int mt = 0; mt < 2; ++mt)
#pragma unroll
      for (int nt = 0; nt < 4; ++nt) {
        int lloc = 64 * wn + 16 * nt + lr;
        int d0 = 32 * wm + 16 * mt + 4 * hi;
        *(ushort4*)&Cl[lloc * 68 + d0] = make_ushort4(f2bf(acc[mt][nt][0]), f2bf(acc[mt][nt][1]),
                                                      f2bf(acc[mt][nt][2]), f2bf(acc[mt][nt][3]));
      }
    __syncthreads();
    int h = m0 >> 6;
    unsigned short* Cb = ((ysel == 0) ? qt : kt) + ((size_t)(bz * NH + h) * SEQLEN + n0) * 64;
    int rr = t >> 1, cc = (t & 1) * 32;
#pragma unroll
    for (int j = 0; j < 4; ++j)
      *(int4*)&Cb[(size_t)rr * 64 + cc + 8 * j] = *(const int4*)&Cl[rr * 68 + cc + 8 * j];
  } else {
    unsigned short* Cl2 = lds;
#pragma unroll
    for (int mt = 0; mt < 2; ++mt)
#pragma unroll
      for (int nt = 0; nt < 4; ++nt) {
        int lloc = 64 * wn + 16 * nt + lr;
#pragma unroll
        for (int reg = 0; reg < 4; ++reg)
          Cl2[(32 * wm + 16 * mt + 4 * hi + reg) * 132 + lloc] = f2bf(acc[mt][nt][reg]);
      }
    __syncthreads();
    int dd = t >> 2, cc = (t & 3) * 32;
    unsigned short* Vb = vb + ((size_t)(bz * 512 + m0 + dd)) * SEQLEN + n0;
#pragma unroll
    for (int j = 0; j < 4; ++j)
      *(int4*)&Vb[cc + 8 * j] = *(const int4*)&Cl2[dd * 132 + cc + 8 * j];
  }
}

// ---------------- banded attention, MFMA, unconditional direct-global fragments ----------------
__global__ __launch_bounds__(256) void attn_k(const unsigned short* __restrict__ qt,
                                              const unsigned short* __restrict__ kt,
                                              const unsigned short* __restrict__ vb,
                                              const float* __restrict__ vsum,
                                              unsigned short* __restrict__ attnt) {
  __shared__ alignas(16) unsigned short Ps[64 * 200];
  __shared__ float rowcoef[64];

  int bz = blockIdx.z, hh = blockIdx.y;
  int l0 = blockIdx.x * 64;
  int bh = bz * NH + hh;
  const unsigned short* Qb = qt + (size_t)bh * SEQLEN * 64;
  const unsigned short* Kb = kt + (size_t)bh * SEQLEN * 64;
  const unsigned short* Vp = vb + (size_t)(bz * 512 + hh * 64) * SEQLEN;
  int vsbase = bz * 512 + hh * 64;

  int t = threadIdx.x;
  int w = t >> 6, lane = t & 63, lr = lane & 15, hi = lane >> 4;

  s16x8 a0 = *(const s16x8*)(Qb + ((size_t)(l0 + 16 * w + lr)) * 64 + 8 * hi);
  s16x8 a1 = *(const s16x8*)(Qb + ((size_t)(l0 + 16 * w + lr)) * 64 + 32 + 8 * hi);

  f32x4 sc[12];
#pragma unroll
  for (int ct = 0; ct < 12; ++ct) {
    int m = l0 - 64 + 16 * ct + lr;
    const unsigned short* kp = Kb + (ptrdiff_t)m * 64;
    s16x8 b0 = *(const s16x8*)(kp + 8 * hi);
    s16x8 b1 = *(const s16x8*)(kp + 32 + 8 * hi);
    f32x4 acc = {0.f, 0.f, 0.f, 0.f};
    acc = __builtin_amdgcn_mfma_f32_16x16x32_bf16(a0, b0, acc, 0, 0, 0);
    acc = __builtin_amdgcn_mfma_f32_16x16x32_bf16(a1, b1, acc, 0, 0, 0);
    sc[ct] = acc;
  }

  float rcv[4];
#pragma unroll
  for (int i = 0; i < 4; ++i) {
    int r = 16 * w + 4 * hi + i;
    int l = l0 + r;
    float mx = 0.0f;
    float sv[12];
#pragma unroll
    for (int ct = 0; ct < 12; ++ct) {
      int c = 16 * ct + lr;
      int m = l0 - 64 + c;
      bool ib = (c >= r) && (c <= r + 128) && (m >= 0) && (m < SEQLEN);
      float s = sc[ct][i] * 0.125f;
      sv[ct] = ib ? s : -1e30f;
      mx = ib ? fmaxf(mx, s) : mx;
    }
    mx = fmaxf(mx, __shfl_xor(mx, 1, 64));
    mx = fmaxf(mx, __shfl_xor(mx, 2, 64));
    mx = fmaxf(mx, __shfl_xor(mx, 4, 64));
    mx = fmaxf(mx, __shfl_xor(mx, 8, 64));
    float e0 = expf(-mx);
    float zs = 0.f;
#pragma unroll
    for (int ct = 0; ct < 12; ++ct) {
      float e = (sv[ct] > -1e29f) ? expf(sv[ct] - mx) : 0.0f;
      sv[ct] = e;
      zs += e;
    }
    zs += __shfl_xor(zs, 1, 64);
    zs += __shfl_xor(zs, 2, 64);
    zs += __shfl_xor(zs, 4, 64);
    zs += __shfl_xor(zs, 8, 64);
    int lo = l - NREC; if (lo < 0) lo = 0;
    int hi2 = l + NREC; if (hi2 > SEQLEN - 1) hi2 = SEQLEN - 1;
    float inv = 1.0f / (zs + (float)(SEQLEN - (hi2 - lo + 1)) * e0);
    rcv[i] = e0 * inv;
#pragma unroll
    for (int ct = 0; ct < 12; ++ct)
      sc[ct][i] = (sv[ct] > 0.0f) ? (sv[ct] - e0) * inv : 0.0f;
  }

#pragma unroll
  for (int i = 0; i < 4; ++i) {
    int r = 16 * w + 4 * hi + i;
#pragma unroll
    for (int ct = 0; ct < 12; ++ct)
      Ps[r * 200 + 16 * ct + lr] = f2bf(sc[ct][i]);
  }
  if (lr == 0) {
#pragma unroll
    for (int i = 0; i < 4; ++i) rowcoef[16 * w + 4 * hi + i] = rcv[i];
  }
  __syncthreads();

  s16x8 av[6];
#pragma unroll
  for (int ks = 0; ks < 6; ++ks) {
    int m8 = l0 - 64 + 32 * ks + 8 * hi;
    av[ks] = *(const s16x8*)(Vp + (ptrdiff_t)(16 * w + lr) * SEQLEN + m8);
  }
  float vsv[4];
#pragma unroll
  for (int reg = 0; reg < 4; ++reg) vsv[reg] = vsum[vsbase + 16 * w + 4 * hi + reg];

  unsigned short* Ob = attnt + ((size_t)bz * SEQLEN) * 512 + hh * 64;
#pragma unroll
  for (int nt = 0; nt < 4; ++nt) {
    f32x4 acc = {0.f, 0.f, 0.f, 0.f};
#pragma unroll
    for (int ks = 0; ks < 6; ++ks) {
      s16x8 b = *(const s16x8*)&Ps[(16 * nt + lr) * 200 + 32 * ks + 8 * hi];
      acc = __builtin_amdgcn_mfma_f32_16x16x32_bf16(av[ks], b, acc, 0, 0, 0);
    }
    int l = l0 + 16 * nt + lr;
    float rcf = rowcoef[16 * nt + lr];
    ushort4 o = make_ushort4(f2bf(acc[0] + rcf * vsv[0]), f2bf(acc[1] + rcf * vsv[1]),
                             f2bf(acc[2] + rcf * vsv[2]), f2bf(acc[3] + rcf * vsv[3]));
    *(ushort4*)&Ob[(size_t)l * 512 + 16 * w + 4 * hi] = o;
  }
}

// ---------------- fused tail, wave-per-block (64 threads, 16 l-cols each) ----------------
// All three phases are wave-independent; LDS per block: pred/h slices + g/b.
__global__ __launch_bounds__(64) void tail_k(const unsigned short* __restrict__ wcb,
                                             const unsigned short* __restrict__ wresb,
                                             const unsigned short* __restrict__ w1b,
                                             const unsigned short* __restrict__ w2b,
                                             const unsigned short* __restrict__ attnt,
                                             const unsigned short* __restrict__ xpt,
                                             const float* __restrict__ g1v,
                                             const float* __restrict__ b1v,
                                             const float* __restrict__ g2v,
                                             const float* __restrict__ b2v,
                                             float* __restrict__ outp) {
  __shared__ float gs1[64], bs1[64], gs2[64], bs2[64];
  __shared__ alignas(16) unsigned short pw[16][72];
  __shared__ alignas(16) unsigned short hw[16][264];

  int b = blockIdx.y;
  int l0 = blockIdx.x * 16;
  int t = threadIdx.x;                 // 0..63, one wave
  int lr = t & 15, hi = t >> 4;
  gs1[t] = g1v[t]; bs1[t] = b1v[t]; gs2[t] = g2v[t]; bs2[t] = b2v[t];
  __syncthreads();

  int lloc = lr;
  const unsigned short* brow = attnt + ((size_t)b * SEQLEN + l0 + lloc) * 512;
  const unsigned short* xrow = xpt + ((size_t)b * SEQLEN + l0 + lloc) * 512;

  // ---- phase 1: pred = LN1(Wc @ attnt + Wres @ x) ----
  f32x4 acc[4];
#pragma unroll
  for (int i = 0; i < 4; ++i) acc[i] = (f32x4){0.f, 0.f, 0.f, 0.f};
#pragma unroll
  for (int ks = 0; ks < 16; ++ks) {
    s16x8 bf = *(const s16x8*)(brow + 32 * ks + 8 * hi);
#pragma unroll
    for (int mt = 0; mt < 4; ++mt) {
      s16x8 af = *(const s16x8*)(wcb + (size_t)(16 * mt + lr) * 512 + 32 * ks + 8 * hi);
      acc[mt] = __builtin_amdgcn_mfma_f32_16x16x32_bf16(af, bf, acc[mt], 0, 0, 0);
    }
  }
#pragma unroll
  for (int ks = 0; ks < 8; ++ks) {
    s16x8 bf = *(const s16x8*)(xrow + 32 * ks + 8 * hi);
#pragma unroll
    for (int mt = 0; mt < 4; ++mt) {
      s16x8 af = *(const s16x8*)(wresb + (size_t)(16 * mt + lr) * 256 + 32 * ks + 8 * hi);
      acc[mt] = __builtin_amdgcn_mfma_f32_16x16x32_bf16(af, bf, acc[mt], 0, 0, 0);
    }
  }
  float resid[4][4];
  {
    float sum = 0.f, sq = 0.f;
#pragma unroll
    for (int mt = 0; mt < 4; ++mt)
#pragma unroll
      for (int reg = 0; reg < 4; ++reg) { float v = acc[mt][reg]; sum += v; sq += v * v; }
    sum += __shfl_xor(sum, 16, 64); sq += __shfl_xor(sq, 16, 64);
    sum += __shfl_xor(sum, 32, 64); sq += __shfl_xor(sq, 32, 64);
    float mu = sum * (1.0f / 64.0f);
    float var = sq * (1.0f / 64.0f) - mu * mu;
    float rstd = rsqrtf(var + 1e-5f);
#pragma unroll
    for (int mt = 0; mt < 4; ++mt) {
      float o[4];
#pragma unroll
      for (int reg = 0; reg < 4; ++reg) {
        int m = 16 * mt + 4 * hi + reg;
        o[reg] = (acc[mt][reg] - mu) * rstd * gs1[m] + bs1[m];
        resid[mt][reg] = o[reg];
      }
      *(ushort4*)&pw[lr][16 * mt + 4 * hi] =
          make_ushort4(f2bf(o[0]), f2bf(o[1]), f2bf(o[2]), f2bf(o[3]));
    }
  }
  __syncthreads();

  // ---- phase 2: h = gelu(W1 @ pred) ----
  {
    s16x8 bf0 = *(const s16x8*)&pw[lr][8 * hi];
    s16x8 bf1 = *(const s16x8*)&pw[lr][32 + 8 * hi];
#pragma unroll
    for (int mt = 0; mt < 16; ++mt) {
      s16x8 a0 = *(const s16x8*)(w1b + (size_t)(16 * mt + lr) * 64 + 8 * hi);
      s16x8 a1 = *(const s16x8*)(w1b + (size_t)(16 * mt + lr) * 64 + 32 + 8 * hi);
      f32x4 a2 = {0.f, 0.f, 0.f, 0.f};
      a2 = __builtin_amdgcn_mfma_f32_16x16x32_bf16(a0, bf0, a2, 0, 0, 0);
      a2 = __builtin_amdgcn_mfma_f32_16x16x32_bf16(a1, bf1, a2, 0, 0, 0);
      float v0 = a2[0], v1 = a2[1], v2 = a2[2], v3 = a2[3];
      v0 = 0.5f * v0 * (1.0f + erff(v0 * 0.70710678118654752440f));
      v1 = 0.5f * v1 * (1.0f + erff(v1 * 0.70710678118654752440f));
      v2 = 0.5f * v2 * (1.0f + erff(v2 * 0.70710678118654752440f));
      v3 = 0.5f * v3 * (1.0f + erff(v3 * 0.70710678118654752440f));
      *(ushort4*)&hw[lr][16 * mt + 4 * hi] = make_ushort4(f2bf(v0), f2bf(v1), f2bf(v2), f2bf(v3));
    }
  }
  __syncthreads();

  // ---- phase 3: out = LN2(W2 @ h + pred) ----
  f32x4 acc3[4];
#pragma unroll
  for (int i = 0; i < 4; ++i) acc3[i] = (f32x4){0.f, 0.f, 0.f, 0.f};
#pragma unroll
  for (int ks = 0; ks < 8; ++ks) {
    s16x8 bf = *(const s16x8*)&hw[lr][32 * ks + 8 * hi];
#pragma unroll
    for (int mt = 0; mt < 4; ++mt) {
      s16x8 af = *(const s16x8*)(w2b + (size_t)(16 * mt + lr) * 256 + 32 * ks + 8 * hi);
      acc3[mt] = __builtin_amdgcn_mfma_f32_16x16x32_bf16(af, bf, acc3[mt], 0, 0, 0);
    }
  }
#pragma unroll
  for (int mt = 0; mt < 4; ++mt)
#pragma unroll
    for (int reg = 0; reg < 4; ++reg) acc3[mt][reg] += resid[mt][reg];
  float sum = 0.f, sq = 0.f;
#pragma unroll
  for (int mt = 0; mt < 4; ++mt)
#pragma unroll
    for (int reg = 0; reg < 4; ++reg) { float v = acc3[mt][reg]; sum += v; sq += v * v; }
  sum += __shfl_xor(sum, 16, 64); sq += __shfl_xor(sq, 16, 64);
  sum += __shfl_xor(sum, 32, 64); sq += __shfl_xor(sq, 32, 64);
  float mu = sum * (1.0f / 64.0f);
  float var = sq * (1.0f / 64.0f) - mu * mu;
  float rstd = rsqrtf(var + 1e-5f);
  float* ob = outp + (size_t)b * 64 * SEQLEN;
  int l = l0 + lloc;
#pragma unroll
  for (int mt = 0; mt < 4; ++mt)
#pragma unroll
    for (int reg = 0; reg < 4; ++reg) {
      int m = 16 * mt + 4 * hi + reg;
      ob[(size_t)m * SEQLEN + l] = (acc3[mt][reg] - mu) * rstd * gs2[m] + bs2[m];
    }
}

extern "C" void kernel_launch(void* const* d_in, const int* in_sizes, int n_in,
                              void* d_out, int out_size, void* d_ws, size_t ws_size,
                              hipStream_t stream) {
  const float* x    = (const float*)d_in[0];
  const float* Wq   = (const float*)d_in[1];
  const float* Wk   = (const float*)d_in[2];
  const float* Wv   = (const float*)d_in[3];
  const float* Wres = (const float*)d_in[4];
  const float* Wc   = (const float*)d_in[5];
  const float* ln1g = (const float*)d_in[6];
  const float* ln1b = (const float*)d_in[7];
  const float* W1   = (const float*)d_in[8];
  const float* W2   = (const float*)d_in[9];
  const float* ln2g = (const float*)d_in[10];
  const float* ln2b = (const float*)d_in[11];

  char* base = (char*)d_ws;
  unsigned short* xpt   = (unsigned short*)base; base += (size_t)2097152 * 2;
  unsigned short* wqb   = (unsigned short*)base; base += (size_t)262144 * 2;
  unsigned short* wkb   = (unsigned short*)base; base += (size_t)262144 * 2;
  unsigned short* wvb   = (unsigned short*)base; base += (size_t)262144 * 2;
  unsigned short* wcb   = (unsigned short*)base; base += (size_t)32768 * 2;
  unsigned short* wresb = (unsigned short*)base; base += (size_t)16384 * 2;
  unsigned short* w1b   = (unsigned short*)base; base += (size_t)16384 * 2;
  unsigned short* w2b   = (unsigned short*)base; base += (size_t)16384 * 2;
  unsigned short* qt    = (unsigned short*)base; base += (size_t)2097152 * 2;
  unsigned short* kt    = (unsigned short*)base; base += (size_t)2097152 * 2;
  unsigned short* vbb   = (unsigned short*)base; base += (size_t)2097152 * 2;
  float* vsum           = (float*)base;          base += (size_t)1024 * 4;
  unsigned short* attnt = (unsigned short*)base; base += (size_t)2097152 * 2;
  float* outp = (float*)d_out;

  prep_k<<<1361, 256, 0, stream>>>(x, Wq, Wk, Wv, Wc, Wres, W1, W2,
                                   xpt, wqb, wkb, wvb, wcb, wresb, w1b, w2b, vsum);
  qkv_gemm_k<<<dim3(16, 24, NBATCH), 256, 0, stream>>>(wqb, wkb, wvb, xpt, qt, kt, vbb, vsum);
  attn_k<<<dim3(32, NH, NBATCH), 256, 0, stream>>>(qt, kt, vbb, vsum, attnt);
  tail_k<<<dim3(128, NBATCH), 64, 0, stream>>>(wcb, wresb, w1b, w2b, attnt, xpt,
                                               ln1g, ln1b, ln2g, ln2b, outp);
}

// Round 11
// 70.683 us; speedup vs baseline: 1.5418x; 1.0126x over previous
//
#include <hip/hip_runtime.h>
#include <cstdint>
#include <cstddef>

// ---- problem constants ----
#define SEQLEN 2048
#define NBATCH 2
#define NIND   256
#define NPOS   256
#define NCIN   512
#define NH     8
#define NDE    64
#define NDV    64
#define NREC   64

typedef __attribute__((ext_vector_type(8))) short s16x8;
typedef __attribute__((ext_vector_type(4))) float f32x4;

__device__ __forceinline__ unsigned short f2bf(float f) {
  union { float f; unsigned u; } v; v.f = f;
  unsigned r = v.u + 0x7fffu + ((v.u >> 16) & 1u);
  return (unsigned short)(r >> 16);
}

// async global->LDS, 16B per lane; LDS dest = wave-uniform base + lane*16
__device__ __forceinline__ void gload16(const unsigned short* g, unsigned short* l) {
  __builtin_amdgcn_global_load_lds(
      (const __attribute__((address_space(1))) unsigned int*)g,
      (__attribute__((address_space(3))) unsigned int*)l, 16, 0, 0);
}

// ---------------- prep: concat+pos transpose, all weight cvts, vsum zero ----------------
__global__ __launch_bounds__(256) void prep_k(const float* __restrict__ x,
                                              const float* __restrict__ Wq,
                                              const float* __restrict__ Wk,
                                              const float* __restrict__ Wv,
                                              const float* __restrict__ Wc,
                                              const float* __restrict__ Wres,
                                              const float* __restrict__ W1,
                                              const float* __restrict__ W2,
                                              unsigned short* __restrict__ xpt,
                                              unsigned short* __restrict__ wqb,
                                              unsigned short* __restrict__ wkb,
                                              unsigned short* __restrict__ wvb,
                                              unsigned short* __restrict__ wcb,
                                              unsigned short* __restrict__ wresb,
                                              unsigned short* __restrict__ w1b,
                                              unsigned short* __restrict__ w2b,
                                              float* __restrict__ vsum) {
  __shared__ float tile[64][65];
  int blk = blockIdx.x;
  int t = threadIdx.x;
  if (blk < 512) {
    int b = blk >> 8, c0 = ((blk >> 5) & 7) * 64, l0 = (blk & 31) * 64;
    if (c0 < NIND) {
      const float* src = x + ((size_t)b * NIND + c0) * SEQLEN;
      int ll = t & 63, cq = t >> 6;
#pragma unroll
      for (int i = 0; i < 16; ++i) {
        int cl = cq * 16 + i;
        tile[cl][ll] = src[(size_t)cl * SEQLEN + l0 + ll];
      }
      __syncthreads();
      int cl2 = t & 63, lq = t >> 6;
      unsigned short* dst = xpt + ((size_t)b * SEQLEN + l0) * NCIN + c0;
#pragma unroll
      for (int i = 0; i < 16; ++i) {
        int l = lq * 16 + i;
        dst[(size_t)l * NCIN + cl2] = f2bf(tile[cl2][l]);
      }
    } else {
      if (b == 1) return;              // pos is batch-independent; b==0 block writes both
      int c = c0 + (t & 63);
      int j = c - NIND;
      int i = (j < NPOS / 2) ? j : j - NPOS / 2;
      const double base = (double)1.2f;
      double p = 1.0;
      for (int tt = 0; tt <= i; ++tt) p *= base;
      float w = 0.8f + (float)p;
      float swl = (float)SEQLEN / w;
      const float two_pi = (float)(2.0 * 3.14159265358979323846);
      int wv = t >> 6;
      unsigned short* dst0 = xpt;
      unsigned short* dst1 = xpt + (size_t)SEQLEN * NCIN;
#pragma unroll
      for (int it = 0; it < 16; ++it) {
        int l = l0 + 16 * wv + it;
        float arg = (two_pi * (float)l) / swl;
        unsigned short val = f2bf((j < NPOS / 2) ? sinf(arg) : cosf(arg));
        dst0[(size_t)l * NCIN + c] = val;
        dst1[(size_t)l * NCIN + c] = val;
      }
    }
  } else if (blk == 1360) {
    ((float4*)vsum)[t] = make_float4(0.f, 0.f, 0.f, 0.f);
  } else {
    const float* in;
    unsigned short* out;
    int idx4;
    if (blk < 1280) {
      int i = (blk - 512) * 256 + t;
      int which = i >> 16;
      idx4 = i & 65535;
      in = (which == 0) ? Wq : ((which == 1) ? Wk : Wv);
      out = (which == 0) ? wqb : ((which == 1) ? wkb : wvb);
    } else if (blk < 1312) { in = Wc;   out = wcb;   idx4 = (blk - 1280) * 256 + t; }
    else if (blk < 1328)   { in = Wres; out = wresb; idx4 = (blk - 1312) * 256 + t; }
    else if (blk < 1344)   { in = W1;   out = w1b;   idx4 = (blk - 1328) * 256 + t; }
    else                   { in = W2;   out = w2b;   idx4 = (blk - 1344) * 256 + t; }
    float4 v = ((const float4*)in)[idx4];
    ((ushort4*)out)[idx4] = make_ushort4(f2bf(v.x), f2bf(v.y), f2bf(v.z), f2bf(v.w));
  }
}

// ---------------- fused QKV MFMA GEMM: 64x128, BK=64, 2-deep counted-vmcnt pipeline ----------------
// Prologue stages tiles 0,1 (12 DMAs in flight). Loop: vmcnt(6) waits ONLY for the
// current tile, raw s_barrier, MFMA, raw s_barrier, stage tile it+2 into the buffer
// just consumed. Loads stay in flight across barriers (T3/T4; never vmcnt(0) mid-loop).
__global__ __launch_bounds__(256) void qkv_gemm_k(const unsigned short* __restrict__ Wqb,
                                                  const unsigned short* __restrict__ Wkb,
                                                  const unsigned short* __restrict__ Wvb,
                                                  const unsigned short* __restrict__ xpt,
                                                  unsigned short* __restrict__ qt,
                                                  unsigned short* __restrict__ kt,
                                                  unsigned short* __restrict__ vb,
                                                  float* __restrict__ vsum) {
  __shared__ alignas(16) unsigned short lds[24576];   // 2 x (A 64x64 | B 128x64)

  int bz = blockIdx.z;
  int y = blockIdx.y;
  int ysel = y >> 3;
  int m0 = (y & 7) * 64;
  int n0 = blockIdx.x * 128;
  const unsigned short* W = (ysel == 0) ? Wqb : ((ysel == 1) ? Wkb : Wvb);
  const unsigned short* Bg = xpt + (size_t)bz * SEQLEN * NCIN;

  int t = threadIdx.x;
  int w = t >> 6, lane = t & 63, lr = lane & 15, hi = lane >> 4;
  int wm = w >> 1, wn = w & 1;

  int sr = lane >> 3;
  int scs = ((lane & 7) ^ sr) * 8;   // shorts, source pre-swizzled by row
  const unsigned short* gA0 = W  + (size_t)(m0 + 16 * w + sr) * 512 + scs;
  const unsigned short* gB0 = Bg + (size_t)(n0 + 32 * w + sr) * 512 + scs;

  int swz = (lr & 7) << 3;           // read-side XOR (shorts)

  f32x4 acc[2][4];
#pragma unroll
  for (int i = 0; i < 2; ++i)
#pragma unroll
    for (int j = 0; j < 4; ++j) acc[i][j] = (f32x4){0.f, 0.f, 0.f, 0.f};

  auto stage = [&](int buf, int k0) {
    unsigned short* Ad = lds + buf * 12288 + (16 * w) * 64;
    unsigned short* Bd = lds + buf * 12288 + 4096 + (32 * w) * 64;
    gload16(gA0 + k0,            Ad);
    gload16(gA0 + k0 + 8 * 512,  Ad + 8 * 64);
    gload16(gB0 + k0,            Bd);
    gload16(gB0 + k0 + 8 * 512,  Bd + 8 * 64);
    gload16(gB0 + k0 + 16 * 512, Bd + 16 * 64);
    gload16(gB0 + k0 + 24 * 512, Bd + 24 * 64);
  };
  auto compute = [&](int buf) {
    const unsigned short* Ar = lds + buf * 12288;
    const unsigned short* Br = Ar + 4096;
#pragma unroll
    for (int ks = 0; ks < 2; ++ks) {
      s16x8 af[2], bfv[4];
#pragma unroll
      for (int mt = 0; mt < 2; ++mt)
        af[mt] = *(const s16x8*)&Ar[(32 * wm + 16 * mt + lr) * 64 + ((32 * ks + 8 * hi) ^ swz)];
#pragma unroll
      for (int nt = 0; nt < 4; ++nt)
        bfv[nt] = *(const s16x8*)&Br[(64 * wn + 16 * nt + lr) * 64 + ((32 * ks + 8 * hi) ^ swz)];
#pragma unroll
      for (int mt = 0; mt < 2; ++mt)
#pragma unroll
        for (int nt = 0; nt < 4; ++nt)
          acc[mt][nt] = __builtin_amdgcn_mfma_f32_16x16x32_bf16(af[mt], bfv[nt], acc[mt][nt], 0, 0, 0);
    }
  };

  stage(0, 0);
  stage(1, 64);                       // 12 DMAs in flight
#pragma unroll
  for (int it = 0; it < 8; ++it) {
    if (it < 7) {
      asm volatile("s_waitcnt vmcnt(6)" ::: "memory");   // tile-it landed; tile-it+1 stays in flight
    } else {
      asm volatile("s_waitcnt vmcnt(0)" ::: "memory");   // final tile
    }
    __builtin_amdgcn_s_barrier();     // all waves' tile-it DMAs visible
    compute(it & 1);
    __builtin_amdgcn_s_barrier();     // all waves done reading buf(it&1)
    if (it < 6) stage(it & 1, (it + 2) * 64);            // overwrite consumed buffer
  }
  __syncthreads();                    // retire everything before LDS reuse

  if (ysel == 2) {
#pragma unroll
    for (int mt = 0; mt < 2; ++mt)
#pragma unroll
      for (int reg = 0; reg < 4; ++reg) {
        float p = acc[mt][0][reg] + acc[mt][1][reg] + acc[mt][2][reg] + acc[mt][3][reg];
        p += __shfl_xor(p, 1, 64);
        p += __shfl_xor(p, 2, 64);
        p += __shfl_xor(p, 4, 64);
        p += __shfl_xor(p, 8, 64);
        if (lr == 0)
          atomicAdd(&vsum[bz * 512 + m0 + 32 * wm + 16 * mt + 4 * hi + reg], p);
      }
  }

  if (ysel < 2) {
    unsigned short* Cl = lds;
#pragma unroll
    for (int mt = 0; mt < 2; ++mt)
#pragma unroll
      for (int nt = 0; nt < 4; ++nt) {
        int lloc = 64 * wn + 16 * nt + lr;
        int d0 = 32 * wm + 16 * mt + 4 * hi;
        *(ushort4*)&Cl[lloc * 68 + d0] = make_ushort4(f2bf(acc[mt][nt][0]), f2bf(acc[mt][nt][1]),
                                                      f2bf(acc[mt][nt][2]), f2bf(acc[mt][nt][3]));
      }
    __syncthreads();
    int h = m0 >> 6;
    unsigned short* Cb = ((ysel == 0) ? qt : kt) + ((size_t)(bz * NH + h) * SEQLEN + n0) * 64;
    int rr = t >> 1, cc = (t & 1) * 32;
#pragma unroll
    for (int j = 0; j < 4; ++j)
      *(int4*)&Cb[(size_t)rr * 64 + cc + 8 * j] = *(const int4*)&Cl[rr * 68 + cc + 8 * j];
  } else {
    unsigned short* Cl2 = lds;
#pragma unroll
    for (int mt = 0; mt < 2; ++mt)
#pragma unroll
      for (int nt = 0; nt < 4; ++nt) {
        int lloc = 64 * wn + 16 * nt + lr;
#pragma unroll
        for (int reg = 0; reg < 4; ++reg)
          Cl2[(32 * wm + 16 * mt + 4 * hi + reg) * 132 + lloc] = f2bf(acc[mt][nt][reg]);
      }
    __syncthreads();
    int dd = t >> 2, cc = (t & 3) * 32;
    unsigned short* Vb = vb + ((size_t)(bz * 512 + m0 + dd)) * SEQLEN + n0;
#pragma unroll
    for (int j = 0; j < 4; ++j)
      *(int4*)&Vb[cc + 8 * j] = *(const int4*)&Cl2[dd * 132 + cc + 8 * j];
  }
}

// ---------------- banded attention, MFMA, unconditional direct-global fragments ----------------
__global__ __launch_bounds__(256) void attn_k(const unsigned short* __restrict__ qt,
                                              const unsigned short* __restrict__ kt,
                                              const unsigned short* __restrict__ vb,
                                              const float* __restrict__ vsum,
                                              unsigned short* __restrict__ attnt) {
  __shared__ alignas(16) unsigned short Ps[64 * 200];
  __shared__ float rowcoef[64];

  int bz = blockIdx.z, hh = blockIdx.y;
  int l0 = blockIdx.x * 64;
  int bh = bz * NH + hh;
  const unsigned short* Qb = qt + (size_t)bh * SEQLEN * 64;
  const unsigned short* Kb = kt + (size_t)bh * SEQLEN * 64;
  const unsigned short* Vp = vb + (size_t)(bz * 512 + hh * 64) * SEQLEN;
  int vsbase = bz * 512 + hh * 64;

  int t = threadIdx.x;
  int w = t >> 6, lane = t & 63, lr = lane & 15, hi = lane >> 4;

  s16x8 a0 = *(const s16x8*)(Qb + ((size_t)(l0 + 16 * w + lr)) * 64 + 8 * hi);
  s16x8 a1 = *(const s16x8*)(Qb + ((size_t)(l0 + 16 * w + lr)) * 64 + 32 + 8 * hi);

  f32x4 sc[12];
#pragma unroll
  for (int ct = 0; ct < 12; ++ct) {
    int m = l0 - 64 + 16 * ct + lr;
    const unsigned short* kp = Kb + (ptrdiff_t)m * 64;
    s16x8 b0 = *(const s16x8*)(kp + 8 * hi);
    s16x8 b1 = *(const s16x8*)(kp + 32 + 8 * hi);
    f32x4 acc = {0.f, 0.f, 0.f, 0.f};
    acc = __builtin_amdgcn_mfma_f32_16x16x32_bf16(a0, b0, acc, 0, 0, 0);
    acc = __builtin_amdgcn_mfma_f32_16x16x32_bf16(a1, b1, acc, 0, 0, 0);
    sc[ct] = acc;
  }

  float rcv[4];
#pragma unroll
  for (int i = 0; i < 4; ++i) {
    int r = 16 * w + 4 * hi + i;
    int l = l0 + r;
    float mx = 0.0f;
    float sv[12];
#pragma unroll
    for (int ct = 0; ct < 12; ++ct) {
      int c = 16 * ct + lr;
      int m = l0 - 64 + c;
      bool ib = (c >= r) && (c <= r + 128) && (m >= 0) && (m < SEQLEN);
      float s = sc[ct][i] * 0.125f;
      sv[ct] = ib ? s : -1e30f;
      mx = ib ? fmaxf(mx, s) : mx;
    }
    mx = fmaxf(mx, __shfl_xor(mx, 1, 64));
    mx = fmaxf(mx, __shfl_xor(mx, 2, 64));
    mx = fmaxf(mx, __shfl_xor(mx, 4, 64));
    mx = fmaxf(mx, __shfl_xor(mx, 8, 64));
    float e0 = expf(-mx);
    float zs = 0.f;
#pragma unroll
    for (int ct = 0; ct < 12; ++ct) {
      float e = (sv[ct] > -1e29f) ? expf(sv[ct] - mx) : 0.0f;
      sv[ct] = e;
      zs += e;
    }
    zs += __shfl_xor(zs, 1, 64);
    zs += __shfl_xor(zs, 2, 64);
    zs += __shfl_xor(zs, 4, 64);
    zs += __shfl_xor(zs, 8, 64);
    int lo = l - NREC; if (lo < 0) lo = 0;
    int hi2 = l + NREC; if (hi2 > SEQLEN - 1) hi2 = SEQLEN - 1;
    float inv = 1.0f / (zs + (float)(SEQLEN - (hi2 - lo + 1)) * e0);
    rcv[i] = e0 * inv;
#pragma unroll
    for (int ct = 0; ct < 12; ++ct)
      sc[ct][i] = (sv[ct] > 0.0f) ? (sv[ct] - e0) * inv : 0.0f;
  }

#pragma unroll
  for (int i = 0; i < 4; ++i) {
    int r = 16 * w + 4 * hi + i;
#pragma unroll
    for (int ct = 0; ct < 12; ++ct)
      Ps[r * 200 + 16 * ct + lr] = f2bf(sc[ct][i]);
  }
  if (lr == 0) {
#pragma unroll
    for (int i = 0; i < 4; ++i) rowcoef[16 * w + 4 * hi + i] = rcv[i];
  }
  __syncthreads();

  s16x8 av[6];
#pragma unroll
  for (int ks = 0; ks < 6; ++ks) {
    int m8 = l0 - 64 + 32 * ks + 8 * hi;
    av[ks] = *(const s16x8*)(Vp + (ptrdiff_t)(16 * w + lr) * SEQLEN + m8);
  }
  float vsv[4];
#pragma unroll
  for (int reg = 0; reg < 4; ++reg) vsv[reg] = vsum[vsbase + 16 * w + 4 * hi + reg];

  unsigned short* Ob = attnt + ((size_t)bz * SEQLEN) * 512 + hh * 64;
#pragma unroll
  for (int nt = 0; nt < 4; ++nt) {
    f32x4 acc = {0.f, 0.f, 0.f, 0.f};
#pragma unroll
    for (int ks = 0; ks < 6; ++ks) {
      s16x8 b = *(const s16x8*)&Ps[(16 * nt + lr) * 200 + 32 * ks + 8 * hi];
      acc = __builtin_amdgcn_mfma_f32_16x16x32_bf16(av[ks], b, acc, 0, 0, 0);
    }
    int l = l0 + 16 * nt + lr;
    float rcf = rowcoef[16 * nt + lr];
    ushort4 o = make_ushort4(f2bf(acc[0] + rcf * vsv[0]), f2bf(acc[1] + rcf * vsv[1]),
                             f2bf(acc[2] + rcf * vsv[2]), f2bf(acc[3] + rcf * vsv[3]));
    *(ushort4*)&Ob[(size_t)l * 512 + 16 * w + 4 * hi] = o;
  }
}

// ---------------- fused tail, wave-per-block (64 threads, 16 l-cols each) ----------------
__global__ __launch_bounds__(64) void tail_k(const unsigned short* __restrict__ wcb,
                                             const unsigned short* __restrict__ wresb,
                                             const unsigned short* __restrict__ w1b,
                                             const unsigned short* __restrict__ w2b,
                                             const unsigned short* __restrict__ attnt,
                                             const unsigned short* __restrict__ xpt,
                                             const float* __restrict__ g1v,
                                             const float* __restrict__ b1v,
                                             const float* __restrict__ g2v,
                                             const float* __restrict__ b2v,
                                             float* __restrict__ outp) {
  __shared__ float gs1[64], bs1[64], gs2[64], bs2[64];
  __shared__ alignas(16) unsigned short pw[16][72];
  __shared__ alignas(16) unsigned short hw[16][264];

  int b = blockIdx.y;
  int l0 = blockIdx.x * 16;
  int t = threadIdx.x;                 // 0..63, one wave
  int lr = t & 15, hi = t >> 4;
  gs1[t] = g1v[t]; bs1[t] = b1v[t]; gs2[t] = g2v[t]; bs2[t] = b2v[t];
  __syncthreads();

  int lloc = lr;
  const unsigned short* brow = attnt + ((size_t)b * SEQLEN + l0 + lloc) * 512;
  const unsigned short* xrow = xpt + ((size_t)b * SEQLEN + l0 + lloc) * 512;

  // ---- phase 1: pred = LN1(Wc @ attnt + Wres @ x) ----
  f32x4 acc[4];
#pragma unroll
  for (int i = 0; i < 4; ++i) acc[i] = (f32x4){0.f, 0.f, 0.f, 0.f};
#pragma unroll
  for (int ks = 0; ks < 16; ++ks) {
    s16x8 bf = *(const s16x8*)(brow + 32 * ks + 8 * hi);
#pragma unroll
    for (int mt = 0; mt < 4; ++mt) {
      s16x8 af = *(const s16x8*)(wcb + (size_t)(16 * mt + lr) * 512 + 32 * ks + 8 * hi);
      acc[mt] = __builtin_amdgcn_mfma_f32_16x16x32_bf16(af, bf, acc[mt], 0, 0, 0);
    }
  }
#pragma unroll
  for (int ks = 0; ks < 8; ++ks) {
    s16x8 bf = *(const s16x8*)(xrow + 32 * ks + 8 * hi);
#pragma unroll
    for (int mt = 0; mt < 4; ++mt) {
      s16x8 af = *(const s16x8*)(wresb + (size_t)(16 * mt + lr) * 256 + 32 * ks + 8 * hi);
      acc[mt] = __builtin_amdgcn_mfma_f32_16x16x32_bf16(af, bf, acc[mt], 0, 0, 0);
    }
  }
  float resid[4][4];
  {
    float sum = 0.f, sq = 0.f;
#pragma unroll
    for (int mt = 0; mt < 4; ++mt)
#pragma unroll
      for (int reg = 0; reg < 4; ++reg) { float v = acc[mt][reg]; sum += v; sq += v * v; }
    sum += __shfl_xor(sum, 16, 64); sq += __shfl_xor(sq, 16, 64);
    sum += __shfl_xor(sum, 32, 64); sq += __shfl_xor(sq, 32, 64);
    float mu = sum * (1.0f / 64.0f);
    float var = sq * (1.0f / 64.0f) - mu * mu;
    float rstd = rsqrtf(var + 1e-5f);
#pragma unroll
    for (int mt = 0; mt < 4; ++mt) {
      float o[4];
#pragma unroll
      for (int reg = 0; reg < 4; ++reg) {
        int m = 16 * mt + 4 * hi + reg;
        o[reg] = (acc[mt][reg] - mu) * rstd * gs1[m] + bs1[m];
        resid[mt][reg] = o[reg];
      }
      *(ushort4*)&pw[lr][16 * mt + 4 * hi] =
          make_ushort4(f2bf(o[0]), f2bf(o[1]), f2bf(o[2]), f2bf(o[3]));
    }
  }
  __syncthreads();

  // ---- phase 2: h = gelu(W1 @ pred) ----
  {
    s16x8 bf0 = *(const s16x8*)&pw[lr][8 * hi];
    s16x8 bf1 = *(const s16x8*)&pw[lr][32 + 8 * hi];
#pragma unroll
    for (int mt = 0; mt < 16; ++mt) {
      s16x8 a0 = *(const s16x8*)(w1b + (size_t)(16 * mt + lr) * 64 + 8 * hi);
      s16x8 a1 = *(const s16x8*)(w1b + (size_t)(16 * mt + lr) * 64 + 32 + 8 * hi);
      f32x4 a2 = {0.f, 0.f, 0.f, 0.f};
      a2 = __builtin_amdgcn_mfma_f32_16x16x32_bf16(a0, bf0, a2, 0, 0, 0);
      a2 = __builtin_amdgcn_mfma_f32_16x16x32_bf16(a1, bf1, a2, 0, 0, 0);
      float v0 = a2[0], v1 = a2[1], v2 = a2[2], v3 = a2[3];
      v0 = 0.5f * v0 * (1.0f + erff(v0 * 0.70710678118654752440f));
      v1 = 0.5f * v1 * (1.0f + erff(v1 * 0.70710678118654752440f));
      v2 = 0.5f * v2 * (1.0f + erff(v2 * 0.70710678118654752440f));
      v3 = 0.5f * v3 * (1.0f + erff(v3 * 0.70710678118654752440f));
      *(ushort4*)&hw[lr][16 * mt + 4 * hi] = make_ushort4(f2bf(v0), f2bf(v1), f2bf(v2), f2bf(v3));
    }
  }
  __syncthreads();

  // ---- phase 3: out = LN2(W2 @ h + pred) ----
  f32x4 acc3[4];
#pragma unroll
  for (int i = 0; i < 4; ++i) acc3[i] = (f32x4){0.f, 0.f, 0.f, 0.f};
#pragma unroll
  for (int ks = 0; ks < 8; ++ks) {
    s16x8 bf = *(const s16x8*)&hw[lr][32 * ks + 8 * hi];
#pragma unroll
    for (int mt = 0; mt < 4; ++mt) {
      s16x8 af = *(const s16x8*)(w2b + (size_t)(16 * mt + lr) * 256 + 32 * ks + 8 * hi);
      acc3[mt] = __builtin_amdgcn_mfma_f32_16x16x32_bf16(af, bf, acc3[mt], 0, 0, 0);
    }
  }
#pragma unroll
  for (int mt = 0; mt < 4; ++mt)
#pragma unroll
    for (int reg = 0; reg < 4; ++reg) acc3[mt][reg] += resid[mt][reg];
  float sum = 0.f, sq = 0.f;
#pragma unroll
  for (int mt = 0; mt < 4; ++mt)
#pragma unroll
    for (int reg = 0; reg < 4; ++reg) { float v = acc3[mt][reg]; sum += v; sq += v * v; }
  sum += __shfl_xor(sum, 16, 64); sq += __shfl_xor(sq, 16, 64);
  sum += __shfl_xor(sum, 32, 64); sq += __shfl_xor(sq, 32, 64);
  float mu = sum * (1.0f / 64.0f);
  float var = sq * (1.0f / 64.0f) - mu * mu;
  float rstd = rsqrtf(var + 1e-5f);
  float* ob = outp + (size_t)b * 64 * SEQLEN;
  int l = l0 + lloc;
#pragma unroll
  for (int mt = 0; mt < 4; ++mt)
#pragma unroll
    for (int reg = 0; reg < 4; ++reg) {
      int m = 16 * mt + 4 * hi + reg;
      ob[(size_t)m * SEQLEN + l] = (acc3[mt][reg] - mu) * rstd * gs2[m] + bs2[m];
    }
}

extern "C" void kernel_launch(void* const* d_in, const int* in_sizes, int n_in,
                              void* d_out, int out_size, void* d_ws, size_t ws_size,
                              hipStream_t stream) {
  const float* x    = (const float*)d_in[0];
  const float* Wq   = (const float*)d_in[1];
  const float* Wk   = (const float*)d_in[2];
  const float* Wv   = (const float*)d_in[3];
  const float* Wres = (const float*)d_in[4];
  const float* Wc   = (const float*)d_in[5];
  const float* ln1g = (const float*)d_in[6];
  const float* ln1b = (const float*)d_in[7];
  const float* W1   = (const float*)d_in[8];
  const float* W2   = (const float*)d_in[9];
  const float* ln2g = (const float*)d_in[10];
  const float* ln2b = (const float*)d_in[11];

  char* base = (char*)d_ws;
  unsigned short* xpt   = (unsigned short*)base; base += (size_t)2097152 * 2;
  unsigned short* wqb   = (unsigned short*)base; base += (size_t)262144 * 2;
  unsigned short* wkb   = (unsigned short*)base; base += (size_t)262144 * 2;
  unsigned short* wvb   = (unsigned short*)base; base += (size_t)262144 * 2;
  unsigned short* wcb   = (unsigned short*)base; base += (size_t)32768 * 2;
  unsigned short* wresb = (unsigned short*)base; base += (size_t)16384 * 2;
  unsigned short* w1b   = (unsigned short*)base; base += (size_t)16384 * 2;
  unsigned short* w2b   = (unsigned short*)base; base += (size_t)16384 * 2;
  unsigned short* qt    = (unsigned short*)base; base += (size_t)2097152 * 2;
  unsigned short* kt    = (unsigned short*)base; base += (size_t)2097152 * 2;
  unsigned short* vbb   = (unsigned short*)base; base += (size_t)2097152 * 2;
  float* vsum           = (float*)base;          base += (size_t)1024 * 4;
  unsigned short* attnt = (unsigned short*)base; base += (size_t)2097152 * 2;
  float* outp = (float*)d_out;

  prep_k<<<1361, 256, 0, stream>>>(x, Wq, Wk, Wv, Wc, Wres, W1, W2,
                                   xpt, wqb, wkb, wvb, wcb, wresb, w1b, w2b, vsum);
  qkv_gemm_k<<<dim3(16, 24, NBATCH), 256, 0, stream>>>(wqb, wkb, wvb, xpt, qt, kt, vbb, vsum);
  attn_k<<<dim3(32, NH, NBATCH), 256, 0, stream>>>(qt, kt, vbb, vsum, attnt);
  tail_k<<<dim3(128, NBATCH), 64, 0, stream>>>(wcb, wresb, w1b, w2b, attnt, xpt,
                                               ln1g, ln1b, ln2g, ln2b, outp);
}